// Round 7
// baseline (934.061 us; speedup 1.0000x reference)
//
#include <hip/hip_runtime.h>

// Performer linear attention, 32x32x16 MFMA, register-resident features.
// n=2, l=2048, h=8, e=64, m=2048. Dtype runtime-detected (bf16 confirmed).
// ws (floats): flag[16] | c_k[32768] | c_q[32768] | ksum01[4][32768] (reused as pad[4][32768])
//   | kvf01[4][16][64][2048] f32 (reused as po[4][32768][64]) | ksumW[32768] | kvT bf16[16][64][2048]
// R13: TLP round. R12 (chain pipeline) spilled (FETCH/WRITE +22MB = scratch) -> reverted
//     to R10 bodies (best: kv 46us, 70% stall, 4 waves/SIMD, 1 blk/CU). With multicast
//     fixed (R10) the wall is chain latency with nothing else to issue during barriers.
//     Fix: 4-way s-split (kv) / m-split (out) -> 512 blocks = 2 independent blocks/CU
//     (8 waves/SIMD); stats re-tiled to 128 rows/block (grid 512, 2/CU). VGPR capped 64
//     via __launch_bounds__(1024,8). reduce/out2 sum 4 partials. ws ~39MB (<256MB).

#define LL 2048
#define HH 8
#define MM 2048
#define ROWSTR 512  // HH*64

#define NORMC 0.35355339059327373f   // 64^-0.25
#define LOG2E 1.4426950408889634f
#define NORMC2 (NORMC * LOG2E)
#define RATIO 0.022097086912079608f  // 2048^-0.5
#define KEPS 1e-4f
#define REPS (RATIO * KEPS)
#define EPSD 1e-6f

#define KVSPLIT 2097152
#define RSPLIT 32768

typedef __attribute__((ext_vector_type(8))) short short8;
typedef __attribute__((ext_vector_type(16))) float f32x16;

#define MFMA32(a, b, c) __builtin_amdgcn_mfma_f32_32x32x16_bf16((a), (b), (c), 0, 0, 0)

// LDS-only workgroup barrier: drains lgkmcnt but leaves global loads in flight.
__device__ __forceinline__ void wg_barrier_lds() {
    asm volatile("s_waitcnt lgkmcnt(0)" ::: "memory");
    __builtin_amdgcn_s_barrier();
    __builtin_amdgcn_sched_barrier(0);
}

__device__ __forceinline__ f32x16 zero16() {
    f32x16 v;
    #pragma unroll
    for (int i = 0; i < 16; ++i) v[i] = 0.f;
    return v;
}
__device__ __forceinline__ unsigned short f2bf(float f) {  // RNE
    union { float f; unsigned int u; } v; v.f = f;
    unsigned int r = v.u + 0x7fffu + ((v.u >> 16) & 1u);
    return (unsigned short)(r >> 16);
}
__device__ __forceinline__ unsigned int pk2(float lo, float hi) {  // trunc pack
    return __builtin_amdgcn_perm(__float_as_uint(hi), __float_as_uint(lo), 0x07060302u);
}
__device__ __forceinline__ float bf2f(unsigned short u) {
    union { unsigned int ui; float f; } v; v.ui = ((unsigned int)u) << 16; return v.f;
}

// ---- direct global row-fragment load: 8 bf16 at row*stride + off ----
template <bool BF16>
__device__ __forceinline__ short8 row_load8(const void* src, size_t rowbase, int off) {
    if (BF16) {
        return *(const short8*)((const unsigned short*)src + rowbase + off);
    } else {
        const float* p = (const float*)src + rowbase + off;
        float4 f0 = ((const float4*)p)[0], f1 = ((const float4*)p)[1];
        union { unsigned int u[4]; short8 s; } v;
        v.u[0] = pk2(f0.x, f0.y); v.u[1] = pk2(f0.z, f0.w);
        v.u[2] = pk2(f1.x, f1.y); v.u[3] = pk2(f1.z, f1.w);
        return v.s;
    }
}

// ---- 64x64 tile staging into LDS [64][72] bf16 (256-thread pattern) ----
template <bool BF16>
__device__ __forceinline__ void tile_load(const void* src, size_t base, size_t rstride,
                                          int t, uint4& A, uint4& B) {
    const int row = t >> 2, c16 = (t & 3) * 16;
    if (BF16) {
        const unsigned short* p = (const unsigned short*)src + base + (size_t)row * rstride + c16;
        A = *(const uint4*)p;
        B = *(const uint4*)(p + 8);
    } else {
        const float* p = (const float*)src + base + (size_t)row * rstride + c16;
        float4 f0 = ((const float4*)p)[0], f1 = ((const float4*)p)[1];
        float4 f2 = ((const float4*)p)[2], f3 = ((const float4*)p)[3];
        A.x = pk2(f0.x, f0.y); A.y = pk2(f0.z, f0.w);
        A.z = pk2(f1.x, f1.y); A.w = pk2(f1.z, f1.w);
        B.x = pk2(f2.x, f2.y); B.y = pk2(f2.z, f2.w);
        B.z = pk2(f3.x, f3.y); B.w = pk2(f3.z, f3.w);
    }
}
__device__ __forceinline__ void tile_store72(unsigned short* D, int t, uint4 A, uint4 B) {
    const int row = t >> 2, c16 = (t & 3) * 16;
    *(uint4*)&D[row * 72 + c16] = A;
    *(uint4*)&D[row * 72 + c16 + 8] = B;
}

// ---- V transpose staging into LDS [64e][72] (256-thread pattern) ----
template <bool BF16>
__device__ __forceinline__ void vt_load(const void* V, size_t base, int t, uint4& A, uint4& B) {
    const int s0 = (t & 31) * 2, e0 = (t >> 5) * 8;
    if (BF16) {
        const unsigned short* p = (const unsigned short*)V + base + (size_t)s0 * ROWSTR + e0;
        A = *(const uint4*)p;
        B = *(const uint4*)(p + ROWSTR);
    } else {
        const float* p = (const float*)V + base + (size_t)s0 * ROWSTR + e0;
        float4 f0 = ((const float4*)p)[0], f1 = ((const float4*)p)[1];
        const float* q = p + ROWSTR;
        float4 g0 = ((const float4*)q)[0], g1 = ((const float4*)q)[1];
        A.x = pk2(f0.x, f0.y); A.y = pk2(f0.z, f0.w);
        A.z = pk2(f1.x, f1.y); A.w = pk2(f1.z, f1.w);
        B.x = pk2(g0.x, g0.y); B.y = pk2(g0.z, g0.w);
        B.z = pk2(g1.x, g1.y); B.w = pk2(g1.z, g1.w);
    }
}
__device__ __forceinline__ void vt_store72(unsigned short* VT, int t, uint4 A, uint4 B) {
    const int s0 = (t & 31) * 2, e0 = (t >> 5) * 8;
    const unsigned ua[4] = {A.x, A.y, A.z, A.w}, ub[4] = {B.x, B.y, B.z, B.w};
    #pragma unroll
    for (int i = 0; i < 4; ++i) {
        *(unsigned*)&VT[(e0 + 2 * i) * 72 + s0] = (ua[i] & 0xFFFFu) | (ub[i] << 16);
        *(unsigned*)&VT[(e0 + 2 * i + 1) * 72 + s0] = (ua[i] >> 16) | (ub[i] & 0xFFFF0000u);
    }
}

// ---- D-layout -> B-operand exchange (half-wave) ----
__device__ __forceinline__ short8 xfrag(const unsigned int pd[8], int cp, int hi) {
    const unsigned int s0 = hi ? pd[4 * cp + 0] : pd[4 * cp + 2];
    const unsigned int s1 = hi ? pd[4 * cp + 1] : pd[4 * cp + 3];
    const unsigned int r0 = (unsigned int)__shfl_xor((int)s0, 32);
    const unsigned int r1 = (unsigned int)__shfl_xor((int)s1, 32);
    union { unsigned int u[4]; short8 s; } v;
    v.u[0] = hi ? r0 : pd[4 * cp + 0];
    v.u[1] = hi ? r1 : pd[4 * cp + 1];
    v.u[2] = hi ? pd[4 * cp + 2] : r0;
    v.u[3] = hi ? pd[4 * cp + 3] : r1;
    return v.s;
}

// ---------------- dtype detection ----------------
__global__ void LinearAttention_15985868276494_detect(const unsigned short* __restrict__ P,
                                                      float* __restrict__ flag) {
    if (threadIdx.x == 0) {
        int sane = 1;
        #pragma unroll
        for (int i = 0; i < 16; ++i) {
            const unsigned e = (P[2 * i] >> 7) & 0xFF;
            if (e < 101 || e > 141) sane = 0;
        }
        *flag = sane ? 1.0f : 0.0f;
    }
}

// ---------------- stats: c[nh][l]*log2e, 128 rows/block, 8 iters x 4 P-tiles ----------------
// 16 waves: mstrip=w&1 (32-m half of sub-tile), r3=(w>>1)&3 (32-row chunk), tsel=w>>3
// (which pair of the 4 sub-tiles). Each row covered by 4 waves (mstrip x tsel).
// Staging groups grp=w>>2 stage tile grp of next quad. Grid (256,2) -> 2 blocks/CU.
template <bool BF16>
__device__ void stats_impl(const void* X, const void* P, float* cws, char* smem) {
    unsigned short* Ps = (unsigned short*)smem;        // [2][4][4608 shorts]
    float* red = (float*)(smem + 73728);               // [512]
    const int t = threadIdx.x;
    const int w = t >> 6, ln = t & 31, hi = (t >> 5) & 1;
    const int mstrip = w & 1, r3 = (w >> 1) & 3, tsel = w >> 3;
    const int grp = w >> 2, tl = t & 255;
    const int row_base = blockIdx.x * 128;

    short8 xb[4];
    #pragma unroll
    for (int c = 0; c < 4; ++c)
        xb[c] = row_load8<BF16>(X, (size_t)(row_base + r3 * 32 + ln) * 64, 16 * c + 8 * hi);

    uint4 pA, pB;
    {
        uint4 a0, b0;
        tile_load<BF16>(P, (size_t)(grp * 64) * 64, 64, tl, a0, b0);
        tile_store72(Ps + grp * 4608, tl, a0, b0);
        tile_load<BF16>(P, (size_t)((4 + grp) * 64) * 64, 64, tl, pA, pB);
    }
    wg_barrier_lds();

    float rmax = -3e38f;
    for (int i = 0; i < 8; ++i) {
        const int cur = i & 1;
        unsigned short* Pq = Ps + cur * 18432;
        #pragma unroll
        for (int j = 0; j < 2; ++j) {
            unsigned short* Pc = Pq + (tsel * 2 + j) * 4608;
            f32x16 acc = zero16();
            #pragma unroll
            for (int c = 0; c < 4; ++c) {
                const short8 af = *(const short8*)&Pc[(32 * mstrip + ln) * 72 + 16 * c + 8 * hi];
                acc = MFMA32(af, xb[c], acc);
            }
            #pragma unroll
            for (int r = 0; r < 16; ++r) rmax = fmaxf(rmax, acc[r]);
            if (j == 0 && i + 1 < 8) {
                tile_store72(Ps + (cur ^ 1) * 18432 + grp * 4608, tl, pA, pB);
                if (i + 2 < 8)
                    tile_load<BF16>(P, (size_t)(((i + 2) * 4 + grp) * 64) * 64, 64, tl, pA, pB);
            }
        }
        wg_barrier_lds();
    }
    rmax = fmaxf(rmax, __shfl_xor(rmax, 32));
    if (hi == 0) red[w * 32 + ln] = rmax;
    float s2 = 0.f;
    if (mstrip == 0 && tsel == 0) {
        #pragma unroll
        for (int c = 0; c < 4; ++c) {
            union { short8 s; unsigned int u[4]; } uv; uv.s = xb[c];
            #pragma unroll
            for (int i2 = 0; i2 < 4; ++i2) {
                const float lo = bf2f((unsigned short)(uv.u[i2] & 0xFFFF));
                const float hv = bf2f((unsigned short)(uv.u[i2] >> 16));
                s2 = fmaf(lo, lo, s2); s2 = fmaf(hv, hv, s2);
            }
        }
        s2 += __shfl_xor(s2, 32);
    }
    wg_barrier_lds();
    if (mstrip == 0 && tsel == 0 && hi == 0) {
        const float rm = fmaxf(fmaxf(red[(r3 * 2) * 32 + ln], red[(r3 * 2 + 1) * 32 + ln]),
                               fmaxf(red[(8 + r3 * 2) * 32 + ln], red[(8 + r3 * 2 + 1) * 32 + ln]));
        const int rg = row_base + r3 * 32 + ln;
        const int n = rg >> 14, l = (rg >> 3) & 2047, h = rg & 7;
        cws[(size_t)((n << 3) | h) * LL + l] =
            (NORMC * rm + (0.5f * NORMC * NORMC) * s2) * LOG2E;
    }
}

__global__ __launch_bounds__(1024, 8) void LinearAttention_15985868276494_stats(
        const void* K, const void* Q, const void* P, const float* flag,
        float* c_k, float* c_q) {
    extern __shared__ char smem_st[];
    const void* X = (blockIdx.y == 0) ? K : Q;
    float* cws = (blockIdx.y == 0) ? c_k : c_q;
    if (*flag != 0.f) stats_impl<true>(X, P, cws, smem_st);
    else stats_impl<false>(X, P, cws, smem_st);
}

// ---------------- kv: partial kvf[sp][nh][e][m] f32, ksum01 (sp in 0..3) ----------------
// 512 blocks x 1024 thr, 2 blocks/CU. Block owns 256 m-cols; streams 8 K/V s-tiles.
// Decode: xcd=bid&7, rr=bid>>3, gq=rr>>3, mtb=rr&7, g=gq*8+xcd, nh=g>>2, sp=g&3.
// All 8 mtb-blocks of a (nh,sp) group on XCD g%8 -> strip L2-resident (8-way multicast).
// LDS: Ks[2][4608] | VT[2][4608] | cks[2][64]; fin[4*64*33] aliases.
template <bool BF16>
__device__ void kv_impl(const void* K, const void* V, const void* P, const float* cws,
                        float* kvf01, float* ksum01, char* smem) {
    unsigned short* Ks = (unsigned short*)smem;            // [2][4608]
    unsigned short* VT = (unsigned short*)(smem + 18432);  // [2][4608]
    float* cks = (float*)(smem + 36864);                   // [2][64]
    float* fin = (float*)smem;                             // [4*64*33]

    const int t = threadIdx.x;
    const int w = t >> 6, ln = t & 31, hi = (t >> 5) & 1;
    const int w2 = w & 3, ep = w >> 2;
    const int sstrip = w2 & 1, msub = w2 >> 1;
    const int mc = ep * 2 + msub;  // 32-m chunk in [0,8)
    const int bid = blockIdx.x;
    const int xcd = bid & 7, rr = bid >> 3;
    const int gq = rr >> 3, mtb = rr & 7;
    const int g = gq * 8 + xcd;
    const int nh = g >> 2, sp = g & 3;
    const int n = nh >> 3, h = nh & 7;
    const size_t xbase = (size_t)n * (LL * ROWSTR) + (size_t)h * 64;
    const int st0 = sp * 8;
    const int mbase = mtb * 256;

    const bool stK = (t < 256), stV = (t >= 256 && t < 512);
    const int tl = t & 255;

    // P fragments direct from global (rows m = mbase + mc*32 + ln)
    short8 pb[4];
    #pragma unroll
    for (int c = 0; c < 4; ++c)
        pb[c] = row_load8<BF16>(P, (size_t)(mbase + mc * 32 + ln) * 64, 16 * c + 8 * hi);

    uint4 kA, kB, vA, vB; float ckr = 0.f;
    if (stK) {
        tile_load<BF16>(K, xbase + (size_t)(st0 * 64) * ROWSTR, ROWSTR, tl, kA, kB);
        tile_store72(Ks, tl, kA, kB);
        tile_load<BF16>(K, xbase + (size_t)((st0 + 1) * 64) * ROWSTR, ROWSTR, tl, kA, kB);
    } else if (stV) {
        vt_load<BF16>(V, xbase + (size_t)(st0 * 64) * ROWSTR, tl, vA, vB);
        vt_store72(VT, tl, vA, vB);
        vt_load<BF16>(V, xbase + (size_t)((st0 + 1) * 64) * ROWSTR, tl, vA, vB);
    }
    if (t < 64) {
        cks[t] = cws[(size_t)nh * LL + st0 * 64 + t];
        ckr = cws[(size_t)nh * LL + (st0 + 1) * 64 + t];
    }
    wg_barrier_lds();

    const short8 ones = {0x3F80, 0x3F80, 0x3F80, 0x3F80, 0x3F80, 0x3F80, 0x3F80, 0x3F80};
    f32x16 akv0 = zero16(), akv1 = zero16(), aks = zero16();

    for (int i = 0; i < 8; ++i) {
        const int cur = i & 1;
        unsigned short* Kc = Ks + cur * 4608;
        unsigned short* Vc = VT + cur * 4608;
        const float* cc = cks + cur * 64;
        // gemm1: D[s][m] = K . P^T
        f32x16 D = zero16();
        #pragma unroll
        for (int c = 0; c < 4; ++c) {
            const short8 af = *(const short8*)&Kc[(32 * sstrip + ln) * 72 + 16 * c + 8 * hi];
            D = MFMA32(af, pb[c], D);
        }
        // staging: store tile i+1, prefetch tile i+2
        if (i + 1 < 8) {
            if (stK) tile_store72(Ks + (cur ^ 1) * 4608, tl, kA, kB);
            else if (stV) vt_store72(VT + (cur ^ 1) * 4608, tl, vA, vB);
            if (t < 64) cks[(cur ^ 1) * 64 + t] = ckr;
            if (i + 2 < 8) {
                const int st = st0 + i + 2;
                if (stK) tile_load<BF16>(K, xbase + (size_t)(st * 64) * ROWSTR, ROWSTR, tl, kA, kB);
                else if (stV) vt_load<BF16>(V, xbase + (size_t)(st * 64) * ROWSTR, tl, vA, vB);
                if (t < 64) ckr = cws[(size_t)nh * LL + st * 64 + t];
            }
        }
        // exp2 (c pre-scaled by log2e; varies with s = row)
        unsigned int pd[8];
        #pragma unroll
        for (int gIdx = 0; gIdx < 4; ++gIdx) {
            const float4 c4 = *(const float4*)&cc[32 * sstrip + 8 * gIdx + 4 * hi];
            const float ca[4] = {c4.x, c4.y, c4.z, c4.w};
            float f[4];
            #pragma unroll
            for (int b = 0; b < 4; ++b) {
                const float arg = fminf(fmaf(D[4 * gIdx + b], NORMC2, -ca[b]), 0.f);
                f[b] = fmaf(__builtin_amdgcn_exp2f(arg), RATIO, REPS);
            }
            pd[2 * gIdx] = pk2(f[0], f[1]);
            pd[2 * gIdx + 1] = pk2(f[2], f[3]);
        }
        // gemm2: akv[e][m] += V^T . F
        #pragma unroll
        for (int cp = 0; cp < 2; ++cp) {
            const short8 bf = xfrag(pd, cp, hi);
            const int scol = 32 * sstrip + 16 * cp + 8 * hi;
            const short8 v0 = *(const short8*)&Vc[ln * 72 + scol];
            const short8 v1 = *(const short8*)&Vc[(32 + ln) * 72 + scol];
            akv0 = MFMA32(v0, bf, akv0);
            akv1 = MFMA32(v1, bf, akv1);
            aks = MFMA32(ones, bf, aks);
        }
        wg_barrier_lds();
    }
    // epilogue: 4 epochs, each = one 64-m tile handled by its 4 waves via fin
    #pragma unroll 1
    for (int e4 = 0; e4 < 4; ++e4) {
        if (ep == e4) {
            const int slot = (w2 * 64 + (t & 63)) * 33;
            #pragma unroll
            for (int r = 0; r < 16; ++r) fin[slot + r] = akv0[r];
            #pragma unroll
            for (int r = 0; r < 16; ++r) fin[slot + 16 + r] = akv1[r];
            fin[slot + 32] = aks[0];
        }
        wg_barrier_lds();
        if (ep == e4) {
            const int tt = t & 255;
            const int mt = mtb * 4 + e4;
            const int e = tt >> 2;
            const int t16 = e >> 5, e5 = e & 31;
            const int hi_s = (e5 >> 2) & 1;
            const int reg = 16 * t16 + (e5 & 3) + 4 * (e5 >> 3);
            float* dst = kvf01 + (size_t)sp * KVSPLIT + (size_t)nh * (64 * MM)
                       + (size_t)e * MM + mt * 64 + (tt & 3) * 16;
            #pragma unroll
            for (int jq = 0; jq < 4; ++jq) {
                float o[4];
                #pragma unroll
                for (int b = 0; b < 4; ++b) {
                    const int m_local = (tt & 3) * 16 + 4 * jq + b;
                    const int ms = m_local >> 5;
                    const int lane_s = hi_s * 32 + (m_local & 31);
                    o[b] = fin[((2 * ms) * 64 + lane_s) * 33 + reg]
                         + fin[((2 * ms + 1) * 64 + lane_s) * 33 + reg];
                }
                *(float4*)&dst[4 * jq] = make_float4(o[0], o[1], o[2], o[3]);
            }
            if (tt < 64) {
                const int ms = tt >> 5;
                const float val = fin[((2 * ms) * 64 + (tt & 31)) * 33 + 32]
                                + fin[((2 * ms + 1) * 64 + (tt & 31)) * 33 + 32];
                ksum01[(size_t)sp * RSPLIT + (size_t)nh * MM + mt * 64 + tt] = val;
            }
        }
        wg_barrier_lds();
    }
}

__global__ __launch_bounds__(1024, 8) void LinearAttention_15985868276494_kv(
        const void* K, const void* V, const void* P, const float* flag,
        const float* cws, float* kvf01, float* ksum01) {
    extern __shared__ char smem_kv[];
    if (*flag != 0.f) kv_impl<true>(K, V, P, cws, kvf01, ksum01, smem_kv);
    else kv_impl<false>(K, V, P, cws, kvf01, ksum01, smem_kv);
}

// ---------------- reduce: kvT bf16 = sum of 4 splits; ksumW ----------------
__global__ __launch_bounds__(256) void LinearAttention_15985868276494_reduce(
        const float* __restrict__ kvf01, const float* __restrict__ ksum01,
        unsigned short* __restrict__ kvT, float* __restrict__ ksumW) {
    const int gid = blockIdx.x * 256 + threadIdx.x;
    const size_t i4 = (size_t)gid * 4;
    const float4 a = *(const float4*)&kvf01[i4];
    const float4 b = *(const float4*)&kvf01[KVSPLIT + i4];
    const float4 c = *(const float4*)&kvf01[2 * (size_t)KVSPLIT + i4];
    const float4 d = *(const float4*)&kvf01[3 * (size_t)KVSPLIT + i4];
    uint2 o;
    o.x = (unsigned)f2bf(a.x + b.x + c.x + d.x) | ((unsigned)f2bf(a.y + b.y + c.y + d.y) << 16);
    o.y = (unsigned)f2bf(a.z + b.z + c.z + d.z) | ((unsigned)f2bf(a.w + b.w + c.w + d.w) << 16);
    *(uint2*)&kvT[i4] = o;
    if (blockIdx.x < 32) {
        const float4 e = *(const float4*)&ksum01[i4];
        const float4 f = *(const float4*)&ksum01[RSPLIT + i4];
        const float4 g = *(const float4*)&ksum01[2 * RSPLIT + i4];
        const float4 h = *(const float4*)&ksum01[3 * RSPLIT + i4];
        *(float4*)&ksumW[i4] = make_float4(e.x + f.x + g.x + h.x, e.y + f.y + g.y + h.y,
                                           e.z + f.z + g.z + h.z, e.w + f.w + g.w + h.w);
    }
}

// ---------------- out (partial over m-quarter sp): po f32, pad f32 ----------------
// 512 blocks x 1024 thr, 2 blocks/CU. Block owns 256 l-rows; streams 8 m-tiles.
// Decode like kv: nh=g>>2, sp=g&3, lbb=rr&7, mt0=sp*8.
// LDS: Ps[2][4608] | KVs[2][4608] | kss[2][64]; fin aliases.
template <bool BF16>
__device__ void out_impl(const void* Q, const void* P, const float* cqw,
                         const unsigned short* kvT, const float* ksum,
                         float* po, float* pad, char* smem) {
    unsigned short* Ps = (unsigned short*)smem;              // [2][4608]
    unsigned short* KVs = (unsigned short*)(smem + 18432);   // [2][4608]
    unsigned short* kss = (unsigned short*)(smem + 36864);   // [2][64]
    float* fin = (float*)smem;                               // [4*64*33]

    const int t = threadIdx.x;
    const int w = t >> 6, ln = t & 31, hi = (t >> 5) & 1;
    const int w2 = w & 3, ep = w >> 2;
    const int mstrip = w2 & 1, lsub = w2 >> 1;
    const int lc = ep * 2 + lsub;  // 32-l chunk in [0,8)
    const int bid = blockIdx.x;
    const int xcd = bid & 7, rr = bid >> 3;
    const int gq = rr >> 3, lbb = rr & 7;
    const int g = gq * 8 + xcd;
    const int nh = g >> 2, sp = g & 3;
    const int n = nh >> 3, h = nh & 7;
    const size_t qbase = (size_t)n * (LL * ROWSTR) + (size_t)h * 64;
    const size_t kvbase = (size_t)nh * (size_t)(64 * MM);
    const int mt0 = sp * 8;
    const int lbase = lbb * 256;

    const bool stP = (t < 256), stKV = (t >= 256 && t < 512);
    const int tl = t & 255;

    // Q fragments direct from global (rows l = lbase + lc*32 + ln)
    short8 qb[4];
    #pragma unroll
    for (int c = 0; c < 4; ++c)
        qb[c] = row_load8<BF16>(Q, qbase + (size_t)(lbase + lc * 32 + ln) * ROWSTR, 16 * c + 8 * hi);
    const float cq = cqw[(size_t)nh * LL + lbase + lc * 32 + ln];

    uint4 pA, pB, kA, kB; float ksr = 0.f;
    if (stP) {
        tile_load<BF16>(P, (size_t)(mt0 * 64) * 64, 64, tl, pA, pB);
        tile_store72(Ps, tl, pA, pB);
        tile_load<BF16>(P, (size_t)((mt0 + 1) * 64) * 64, 64, tl, pA, pB);
    } else if (stKV) {
        tile_load<true>(kvT, kvbase + mt0 * 64, MM, tl, kA, kB);
        tile_store72(KVs, tl, kA, kB);
        tile_load<true>(kvT, kvbase + (mt0 + 1) * 64, MM, tl, kA, kB);
    }
    if (t < 64) {
        kss[t] = f2bf(ksum[(size_t)nh * MM + mt0 * 64 + t]);
        ksr = ksum[(size_t)nh * MM + (mt0 + 1) * 64 + t];
    }
    wg_barrier_lds();

    f32x16 ao0 = zero16(), ao1 = zero16(), ad = zero16();

    for (int i = 0; i < 8; ++i) {
        const int cur = i & 1;
        unsigned short* Pc = Ps + cur * 4608;
        unsigned short* Kc = KVs + cur * 4608;
        const unsigned short* ksc = kss + cur * 64;
        // gemm1: D[m][l] = P . Q^T
        f32x16 D = zero16();
        #pragma unroll
        for (int c = 0; c < 4; ++c) {
            const short8 af = *(const short8*)&Pc[(32 * mstrip + ln) * 72 + 16 * c + 8 * hi];
            D = MFMA32(af, qb[c], D);
        }
        // staging
        if (i + 1 < 8) {
            if (stP) tile_store72(Ps + (cur ^ 1) * 4608, tl, pA, pB);
            else if (stKV) tile_store72(KVs + (cur ^ 1) * 4608, tl, kA, kB);
            if (t < 64) kss[(cur ^ 1) * 64 + t] = f2bf(ksr);
            if (i + 2 < 8) {
                if (stP) tile_load<BF16>(P, (size_t)((mt0 + i + 2) * 64) * 64, 64, tl, pA, pB);
                else if (stKV) tile_load<true>(kvT, kvbase + (mt0 + i + 2) * 64, MM, tl, kA, kB);
                if (t < 64) ksr = ksum[(size_t)nh * MM + (mt0 + i + 2) * 64 + t];
            }
        }
        // exp2 (cq depends on l = col only)
        unsigned int pd[8];
        #pragma unroll
        for (int gIdx = 0; gIdx < 4; ++gIdx) {
            float f[4];
            #pragma unroll
            for (int b = 0; b < 4; ++b) {
                const float arg = fminf(fmaf(D[4 * gIdx + b], NORMC2, -cq), 0.f);
                f[b] = fmaf(__builtin_amdgcn_exp2f(arg), RATIO, REPS);
            }
            pd[2 * gIdx] = pk2(f[0], f[1]);
            pd[2 * gIdx + 1] = pk2(f[2], f[3]);
        }
        // gemm2: O[e][l] += KV . F ; ad[.][l] += ksum . F
        #pragma unroll
        for (int cp = 0; cp < 2; ++cp) {
            const short8 bf = xfrag(pd, cp, hi);
            const int mcol = 32 * mstrip + 16 * cp + 8 * hi;
            const short8 a0 = *(const short8*)&Kc[ln * 72 + mcol];
            const short8 a1 = *(const short8*)&Kc[(32 + ln) * 72 + mcol];
            const short8 k8 = *(const short8*)&ksc[mcol];
            ao0 = MFMA32(a0, bf, ao0);
            ao1 = MFMA32(a1, bf, ao1);
            ad = MFMA32(k8, bf, ad);
        }
        wg_barrier_lds();
    }
    // epilogue: 4 epochs, each = one 64-l tile
    #pragma unroll 1
    for (int e4 = 0; e4 < 4; ++e4) {
        if (ep == e4) {
            const int slot = (w2 * 64 + (t & 63)) * 33;
            #pragma unroll
            for (int r = 0; r < 16; ++r) fin[slot + r] = ao0[r];
            #pragma unroll
            for (int r = 0; r < 16; ++r) fin[slot + 16 + r] = ao1[r];
            fin[slot + 32] = ad[0];
        }
        wg_barrier_lds();
        if (ep == e4) {
            const int tt = t & 255;
            const int l_local = tt >> 2, eg = tt & 3;
            const int ls = l_local >> 5, lane_l = l_local & 31;
            const float adt = fin[((2 * ls) * 64 + lane_l) * 33 + 32]
                            + fin[((2 * ls + 1) * 64 + lane_l) * 33 + 32];
            const int l = (lbb * 4 + e4) * 64 + l_local;
            const size_t row = (size_t)(n * LL + l) * HH + h;
            if (eg == 0) pad[(size_t)sp * RSPLIT + row] = adt;
            float* dst = po + (size_t)sp * KVSPLIT + row * 64 + eg * 16;
            #pragma unroll
            for (int jq = 0; jq < 4; ++jq) {
                float o[4];
                #pragma unroll
                for (int b = 0; b < 4; ++b) {
                    const int e = eg * 16 + 4 * jq + b;
                    const int t16 = e >> 5, e5 = e & 31;
                    const int hi_s = (e5 >> 2) & 1;
                    const int reg = 16 * t16 + (e5 & 3) + 4 * (e5 >> 3);
                    const int lane_s = hi_s * 32 + lane_l;
                    o[b] = fin[((2 * ls) * 64 + lane_s) * 33 + reg]
                         + fin[((2 * ls + 1) * 64 + lane_s) * 33 + reg];
                }
                *(float4*)&dst[4 * jq] = make_float4(o[0], o[1], o[2], o[3]);
            }
        }
        wg_barrier_lds();
    }
}

__global__ __launch_bounds__(1024, 8) void LinearAttention_15985868276494_out(
        const void* Q, const void* P, const float* flag, const float* cqw,
        const unsigned short* kvT, const float* ksum, float* po, float* pad) {
    extern __shared__ char smem_out[];
    if (*flag != 0.f) out_impl<true>(Q, P, cqw, kvT, ksum, po, pad, smem_out);
    else out_impl<false>(Q, P, cqw, kvT, ksum, po, pad, smem_out);
}

// ---------------- out2: combine 4 m-quarters, normalize, emit ----------------
__global__ __launch_bounds__(256) void LinearAttention_15985868276494_out2(
        const float* __restrict__ po, const float* __restrict__ pad,
        const float* __restrict__ flag, void* __restrict__ outp) {
    const int gid = blockIdx.x * 256 + threadIdx.x;
    const int row = gid >> 2, eg = gid & 3;
    const float adt = pad[row] + pad[RSPLIT + row]
                    + pad[2 * RSPLIT + row] + pad[3 * RSPLIT + row];
    const float z = 1.0f / (adt + EPSD);
    const size_t base = (size_t)row * 64 + eg * 16;
    float vals[16];
    #pragma unroll
    for (int q4 = 0; q4 < 4; ++q4) {
        const float4 a = *(const float4*)&po[base + 4 * q4];
        const float4 b = *(const float4*)&po[KVSPLIT + base + 4 * q4];
        const float4 c = *(const float4*)&po[2 * (size_t)KVSPLIT + base + 4 * q4];
        const float4 d = *(const float4*)&po[3 * (size_t)KVSPLIT + base + 4 * q4];
        vals[4 * q4 + 0] = (a.x + b.x + c.x + d.x) * z;
        vals[4 * q4 + 1] = (a.y + b.y + c.y + d.y) * z;
        vals[4 * q4 + 2] = (a.z + b.z + c.z + d.z) * z;
        vals[4 * q4 + 3] = (a.w + b.w + c.w + d.w) * z;
    }
    if (*flag != 0.f) {
        uint4 o0, o1;
        o0.x = (unsigned)f2bf(vals[0]) | ((unsigned)f2bf(vals[1]) << 16);
        o0.y = (unsigned)f2bf(vals[2]) | ((unsigned)f2bf(vals[3]) << 16);
        o0.z = (unsigned)f2bf(vals[4]) | ((unsigned)f2bf(vals[5]) << 16);
        o0.w = (unsigned)f2bf(vals[6]) | ((unsigned)f2bf(vals[7]) << 16);
        o1.x = (unsigned)f2bf(vals[8]) | ((unsigned)f2bf(vals[9]) << 16);
        o1.y = (unsigned)f2bf(vals[10]) | ((unsigned)f2bf(vals[11]) << 16);
        o1.z = (unsigned)f2bf(vals[12]) | ((unsigned)f2bf(vals[13]) << 16);
        o1.w = (unsigned)f2bf(vals[14]) | ((unsigned)f2bf(vals[15]) << 16);
        unsigned short* op = (unsigned short*)outp + base;
        *(uint4*)op = o0;
        *(uint4*)(op + 8) = o1;
    } else {
        float* op = (float*)outp + base;
        #pragma unroll
        for (int q4 = 0; q4 < 4; ++q4)
            *(float4*)&op[4 * q4] = make_float4(vals[4 * q4], vals[4 * q4 + 1],
                                                vals[4 * q4 + 2], vals[4 * q4 + 3]);
    }
}

extern "C" void kernel_launch(void* const* d_in, const int* in_sizes, int n_in,
                              void* d_out, int out_size, void* d_ws, size_t ws_size,
                              hipStream_t stream) {
    const void* Q = d_in[0];
    const void* K = d_in[1];
    const void* V = d_in[2];
    const void* P = d_in[3];

    float* W = (float*)d_ws;
    float* flag = W;                                  // [16]
    float* c_k = W + 16;                              // [32768]
    float* c_q = c_k + 32768;                         // [32768]
    float* ksum01 = c_q + 32768;                      // [4][32768]; reused as pad
    float* kvf01 = ksum01 + 4 * RSPLIT;               // [4][16][64][2048] f32; reused as po
    float* ksumW = kvf01 + 4 * (size_t)KVSPLIT;       // [32768]
    unsigned short* kvTW = (unsigned short*)(ksumW + RSPLIT);  // [16][64][2048] bf16

    LinearAttention_15985868276494_detect<<<1, 64, 0, stream>>>(
        (const unsigned short*)P, flag);
    LinearAttention_15985868276494_stats<<<dim3(256, 2), 1024, 75776, stream>>>(
        K, Q, P, flag, c_k, c_q);
    LinearAttention_15985868276494_kv<<<dim3(512), 1024, 37376, stream>>>(
        K, V, P, flag, c_k, kvf01, ksum01);
    LinearAttention_15985868276494_reduce<<<2048, 256, 0, stream>>>(
        kvf01, ksum01, kvTW, ksumW);
    LinearAttention_15985868276494_out<<<dim3(512), 1024, 37120, stream>>>(
        Q, P, flag, c_q, kvTW, ksumW, kvf01, ksum01);
    LinearAttention_15985868276494_out2<<<512, 256, 0, stream>>>(
        kvf01, ksum01, flag, d_out);
}

// Round 8
// 212.091 us; speedup vs baseline: 4.4041x; 4.4041x over previous
//
#include <hip/hip_runtime.h>

// Performer linear attention, 32x32x16 MFMA, register-resident features.
// n=2, l=2048, h=8, e=64, m=2048. Dtype runtime-detected (bf16 confirmed).
// ws (floats): flag[16] | c_k[32768] | c_q[32768] | ksum01[4][32768] (reused as pad[4][32768])
//   | kvf01[4][16][64][2048] f32 (reused as po[4][32768][64]) | ksumW[32768] | kvT bf16[16][64][2048]
// R14: TLP retry. R13's __launch_bounds__(1024,8) cut VGPR to 32 -> 48-VGPR accumulators
//     spilled (FETCH 692MB/WRITE 1.3GB scratch) -> 934us; TLP never tested. (1024,4) is the
//     proven 64-VGPR no-spill envelope (R10-R12), and at 64 VGPR the HW already permits
//     8 waves/SIMD -- R10's limiter was the 256-block grid (1 blk/CU), not the bound.
//     Keep R13's 4-way sp-split (512 blocks) + (1024,4): 2 independent blocks/CU
//     (74.8KB LDS < 160KB), barrier-independent -> stall converts to issue.

#define LL 2048
#define HH 8
#define MM 2048
#define ROWSTR 512  // HH*64

#define NORMC 0.35355339059327373f   // 64^-0.25
#define LOG2E 1.4426950408889634f
#define NORMC2 (NORMC * LOG2E)
#define RATIO 0.022097086912079608f  // 2048^-0.5
#define KEPS 1e-4f
#define REPS (RATIO * KEPS)
#define EPSD 1e-6f

#define KVSPLIT 2097152
#define RSPLIT 32768

typedef __attribute__((ext_vector_type(8))) short short8;
typedef __attribute__((ext_vector_type(16))) float f32x16;

#define MFMA32(a, b, c) __builtin_amdgcn_mfma_f32_32x32x16_bf16((a), (b), (c), 0, 0, 0)

// LDS-only workgroup barrier: drains lgkmcnt but leaves global loads in flight.
__device__ __forceinline__ void wg_barrier_lds() {
    asm volatile("s_waitcnt lgkmcnt(0)" ::: "memory");
    __builtin_amdgcn_s_barrier();
    __builtin_amdgcn_sched_barrier(0);
}

__device__ __forceinline__ f32x16 zero16() {
    f32x16 v;
    #pragma unroll
    for (int i = 0; i < 16; ++i) v[i] = 0.f;
    return v;
}
__device__ __forceinline__ unsigned short f2bf(float f) {  // RNE
    union { float f; unsigned int u; } v; v.f = f;
    unsigned int r = v.u + 0x7fffu + ((v.u >> 16) & 1u);
    return (unsigned short)(r >> 16);
}
__device__ __forceinline__ unsigned int pk2(float lo, float hi) {  // trunc pack
    return __builtin_amdgcn_perm(__float_as_uint(hi), __float_as_uint(lo), 0x07060302u);
}
__device__ __forceinline__ float bf2f(unsigned short u) {
    union { unsigned int ui; float f; } v; v.ui = ((unsigned int)u) << 16; return v.f;
}

// ---- direct global row-fragment load: 8 bf16 at row*stride + off ----
template <bool BF16>
__device__ __forceinline__ short8 row_load8(const void* src, size_t rowbase, int off) {
    if (BF16) {
        return *(const short8*)((const unsigned short*)src + rowbase + off);
    } else {
        const float* p = (const float*)src + rowbase + off;
        float4 f0 = ((const float4*)p)[0], f1 = ((const float4*)p)[1];
        union { unsigned int u[4]; short8 s; } v;
        v.u[0] = pk2(f0.x, f0.y); v.u[1] = pk2(f0.z, f0.w);
        v.u[2] = pk2(f1.x, f1.y); v.u[3] = pk2(f1.z, f1.w);
        return v.s;
    }
}

// ---- 64x64 tile staging into LDS [64][72] bf16 (256-thread pattern) ----
template <bool BF16>
__device__ __forceinline__ void tile_load(const void* src, size_t base, size_t rstride,
                                          int t, uint4& A, uint4& B) {
    const int row = t >> 2, c16 = (t & 3) * 16;
    if (BF16) {
        const unsigned short* p = (const unsigned short*)src + base + (size_t)row * rstride + c16;
        A = *(const uint4*)p;
        B = *(const uint4*)(p + 8);
    } else {
        const float* p = (const float*)src + base + (size_t)row * rstride + c16;
        float4 f0 = ((const float4*)p)[0], f1 = ((const float4*)p)[1];
        float4 f2 = ((const float4*)p)[2], f3 = ((const float4*)p)[3];
        A.x = pk2(f0.x, f0.y); A.y = pk2(f0.z, f0.w);
        A.z = pk2(f1.x, f1.y); A.w = pk2(f1.z, f1.w);
        B.x = pk2(f2.x, f2.y); B.y = pk2(f2.z, f2.w);
        B.z = pk2(f3.x, f3.y); B.w = pk2(f3.z, f3.w);
    }
}
__device__ __forceinline__ void tile_store72(unsigned short* D, int t, uint4 A, uint4 B) {
    const int row = t >> 2, c16 = (t & 3) * 16;
    *(uint4*)&D[row * 72 + c16] = A;
    *(uint4*)&D[row * 72 + c16 + 8] = B;
}

// ---- V transpose staging into LDS [64e][72] (256-thread pattern) ----
template <bool BF16>
__device__ __forceinline__ void vt_load(const void* V, size_t base, int t, uint4& A, uint4& B) {
    const int s0 = (t & 31) * 2, e0 = (t >> 5) * 8;
    if (BF16) {
        const unsigned short* p = (const unsigned short*)V + base + (size_t)s0 * ROWSTR + e0;
        A = *(const uint4*)p;
        B = *(const uint4*)(p + ROWSTR);
    } else {
        const float* p = (const float*)V + base + (size_t)s0 * ROWSTR + e0;
        float4 f0 = ((const float4*)p)[0], f1 = ((const float4*)p)[1];
        const float* q = p + ROWSTR;
        float4 g0 = ((const float4*)q)[0], g1 = ((const float4*)q)[1];
        A.x = pk2(f0.x, f0.y); A.y = pk2(f0.z, f0.w);
        A.z = pk2(f1.x, f1.y); A.w = pk2(f1.z, f1.w);
        B.x = pk2(g0.x, g0.y); B.y = pk2(g0.z, g0.w);
        B.z = pk2(g1.x, g1.y); B.w = pk2(g1.z, g1.w);
    }
}
__device__ __forceinline__ void vt_store72(unsigned short* VT, int t, uint4 A, uint4 B) {
    const int s0 = (t & 31) * 2, e0 = (t >> 5) * 8;
    const unsigned ua[4] = {A.x, A.y, A.z, A.w}, ub[4] = {B.x, B.y, B.z, B.w};
    #pragma unroll
    for (int i = 0; i < 4; ++i) {
        *(unsigned*)&VT[(e0 + 2 * i) * 72 + s0] = (ua[i] & 0xFFFFu) | (ub[i] << 16);
        *(unsigned*)&VT[(e0 + 2 * i + 1) * 72 + s0] = (ua[i] >> 16) | (ub[i] & 0xFFFF0000u);
    }
}

// ---- D-layout -> B-operand exchange (half-wave) ----
__device__ __forceinline__ short8 xfrag(const unsigned int pd[8], int cp, int hi) {
    const unsigned int s0 = hi ? pd[4 * cp + 0] : pd[4 * cp + 2];
    const unsigned int s1 = hi ? pd[4 * cp + 1] : pd[4 * cp + 3];
    const unsigned int r0 = (unsigned int)__shfl_xor((int)s0, 32);
    const unsigned int r1 = (unsigned int)__shfl_xor((int)s1, 32);
    union { unsigned int u[4]; short8 s; } v;
    v.u[0] = hi ? r0 : pd[4 * cp + 0];
    v.u[1] = hi ? r1 : pd[4 * cp + 1];
    v.u[2] = hi ? pd[4 * cp + 2] : r0;
    v.u[3] = hi ? pd[4 * cp + 3] : r1;
    return v.s;
}

// ---------------- dtype detection ----------------
__global__ void LinearAttention_15985868276494_detect(const unsigned short* __restrict__ P,
                                                      float* __restrict__ flag) {
    if (threadIdx.x == 0) {
        int sane = 1;
        #pragma unroll
        for (int i = 0; i < 16; ++i) {
            const unsigned e = (P[2 * i] >> 7) & 0xFF;
            if (e < 101 || e > 141) sane = 0;
        }
        *flag = sane ? 1.0f : 0.0f;
    }
}

// ---------------- stats: c[nh][l]*log2e, 128 rows/block, 8 iters x 4 P-tiles ----------------
// 16 waves: mstrip=w&1, r3=(w>>1)&3 (32-row chunk), tsel=w>>3 (sub-tile pair).
// Grid (256,2) = 512 blocks -> 2 blocks/CU (LDS 75.8KB x2 < 160KB).
template <bool BF16>
__device__ void stats_impl(const void* X, const void* P, float* cws, char* smem) {
    unsigned short* Ps = (unsigned short*)smem;        // [2][4][4608 shorts]
    float* red = (float*)(smem + 73728);               // [512]
    const int t = threadIdx.x;
    const int w = t >> 6, ln = t & 31, hi = (t >> 5) & 1;
    const int mstrip = w & 1, r3 = (w >> 1) & 3, tsel = w >> 3;
    const int grp = w >> 2, tl = t & 255;
    const int row_base = blockIdx.x * 128;

    short8 xb[4];
    #pragma unroll
    for (int c = 0; c < 4; ++c)
        xb[c] = row_load8<BF16>(X, (size_t)(row_base + r3 * 32 + ln) * 64, 16 * c + 8 * hi);

    uint4 pA, pB;
    {
        uint4 a0, b0;
        tile_load<BF16>(P, (size_t)(grp * 64) * 64, 64, tl, a0, b0);
        tile_store72(Ps + grp * 4608, tl, a0, b0);
        tile_load<BF16>(P, (size_t)((4 + grp) * 64) * 64, 64, tl, pA, pB);
    }
    wg_barrier_lds();

    float rmax = -3e38f;
    for (int i = 0; i < 8; ++i) {
        const int cur = i & 1;
        unsigned short* Pq = Ps + cur * 18432;
        #pragma unroll
        for (int j = 0; j < 2; ++j) {
            unsigned short* Pc = Pq + (tsel * 2 + j) * 4608;
            f32x16 acc = zero16();
            #pragma unroll
            for (int c = 0; c < 4; ++c) {
                const short8 af = *(const short8*)&Pc[(32 * mstrip + ln) * 72 + 16 * c + 8 * hi];
                acc = MFMA32(af, xb[c], acc);
            }
            #pragma unroll
            for (int r = 0; r < 16; ++r) rmax = fmaxf(rmax, acc[r]);
            if (j == 0 && i + 1 < 8) {
                tile_store72(Ps + (cur ^ 1) * 18432 + grp * 4608, tl, pA, pB);
                if (i + 2 < 8)
                    tile_load<BF16>(P, (size_t)(((i + 2) * 4 + grp) * 64) * 64, 64, tl, pA, pB);
            }
        }
        wg_barrier_lds();
    }
    rmax = fmaxf(rmax, __shfl_xor(rmax, 32));
    if (hi == 0) red[w * 32 + ln] = rmax;
    float s2 = 0.f;
    if (mstrip == 0 && tsel == 0) {
        #pragma unroll
        for (int c = 0; c < 4; ++c) {
            union { short8 s; unsigned int u[4]; } uv; uv.s = xb[c];
            #pragma unroll
            for (int i2 = 0; i2 < 4; ++i2) {
                const float lo = bf2f((unsigned short)(uv.u[i2] & 0xFFFF));
                const float hv = bf2f((unsigned short)(uv.u[i2] >> 16));
                s2 = fmaf(lo, lo, s2); s2 = fmaf(hv, hv, s2);
            }
        }
        s2 += __shfl_xor(s2, 32);
    }
    wg_barrier_lds();
    if (mstrip == 0 && tsel == 0 && hi == 0) {
        const float rm = fmaxf(fmaxf(red[(r3 * 2) * 32 + ln], red[(r3 * 2 + 1) * 32 + ln]),
                               fmaxf(red[(8 + r3 * 2) * 32 + ln], red[(8 + r3 * 2 + 1) * 32 + ln]));
        const int rg = row_base + r3 * 32 + ln;
        const int n = rg >> 14, l = (rg >> 3) & 2047, h = rg & 7;
        cws[(size_t)((n << 3) | h) * LL + l] =
            (NORMC * rm + (0.5f * NORMC * NORMC) * s2) * LOG2E;
    }
}

__global__ __launch_bounds__(1024, 4) void LinearAttention_15985868276494_stats(
        const void* K, const void* Q, const void* P, const float* flag,
        float* c_k, float* c_q) {
    extern __shared__ char smem_st[];
    const void* X = (blockIdx.y == 0) ? K : Q;
    float* cws = (blockIdx.y == 0) ? c_k : c_q;
    if (*flag != 0.f) stats_impl<true>(X, P, cws, smem_st);
    else stats_impl<false>(X, P, cws, smem_st);
}

// ---------------- kv: partial kvf[sp][nh][e][m] f32, ksum01 (sp in 0..3) ----------------
// 512 blocks x 1024 thr, 2 blocks/CU (64 VGPR, 37.4KB LDS). Block owns 256 m-cols;
// streams 8 K/V s-tiles. Decode: g=gq*8+xcd, nh=g>>2, sp=g&3; 8 mtb-blocks/group on 1 XCD.
// LDS: Ks[2][4608] | VT[2][4608] | cks[2][64]; fin[4*64*33] aliases.
template <bool BF16>
__device__ void kv_impl(const void* K, const void* V, const void* P, const float* cws,
                        float* kvf01, float* ksum01, char* smem) {
    unsigned short* Ks = (unsigned short*)smem;            // [2][4608]
    unsigned short* VT = (unsigned short*)(smem + 18432);  // [2][4608]
    float* cks = (float*)(smem + 36864);                   // [2][64]
    float* fin = (float*)smem;                             // [4*64*33]

    const int t = threadIdx.x;
    const int w = t >> 6, ln = t & 31, hi = (t >> 5) & 1;
    const int w2 = w & 3, ep = w >> 2;
    const int sstrip = w2 & 1, msub = w2 >> 1;
    const int mc = ep * 2 + msub;  // 32-m chunk in [0,8)
    const int bid = blockIdx.x;
    const int xcd = bid & 7, rr = bid >> 3;
    const int gq = rr >> 3, mtb = rr & 7;
    const int g = gq * 8 + xcd;
    const int nh = g >> 2, sp = g & 3;
    const int n = nh >> 3, h = nh & 7;
    const size_t xbase = (size_t)n * (LL * ROWSTR) + (size_t)h * 64;
    const int st0 = sp * 8;
    const int mbase = mtb * 256;

    const bool stK = (t < 256), stV = (t >= 256 && t < 512);
    const int tl = t & 255;

    // P fragments direct from global (rows m = mbase + mc*32 + ln)
    short8 pb[4];
    #pragma unroll
    for (int c = 0; c < 4; ++c)
        pb[c] = row_load8<BF16>(P, (size_t)(mbase + mc * 32 + ln) * 64, 16 * c + 8 * hi);

    uint4 kA, kB, vA, vB; float ckr = 0.f;
    if (stK) {
        tile_load<BF16>(K, xbase + (size_t)(st0 * 64) * ROWSTR, ROWSTR, tl, kA, kB);
        tile_store72(Ks, tl, kA, kB);
        tile_load<BF16>(K, xbase + (size_t)((st0 + 1) * 64) * ROWSTR, ROWSTR, tl, kA, kB);
    } else if (stV) {
        vt_load<BF16>(V, xbase + (size_t)(st0 * 64) * ROWSTR, tl, vA, vB);
        vt_store72(VT, tl, vA, vB);
        vt_load<BF16>(V, xbase + (size_t)((st0 + 1) * 64) * ROWSTR, tl, vA, vB);
    }
    if (t < 64) {
        cks[t] = cws[(size_t)nh * LL + st0 * 64 + t];
        ckr = cws[(size_t)nh * LL + (st0 + 1) * 64 + t];
    }
    wg_barrier_lds();

    const short8 ones = {0x3F80, 0x3F80, 0x3F80, 0x3F80, 0x3F80, 0x3F80, 0x3F80, 0x3F80};
    f32x16 akv0 = zero16(), akv1 = zero16(), aks = zero16();

    for (int i = 0; i < 8; ++i) {
        const int cur = i & 1;
        unsigned short* Kc = Ks + cur * 4608;
        unsigned short* Vc = VT + cur * 4608;
        const float* cc = cks + cur * 64;
        // gemm1: D[s][m] = K . P^T
        f32x16 D = zero16();
        #pragma unroll
        for (int c = 0; c < 4; ++c) {
            const short8 af = *(const short8*)&Kc[(32 * sstrip + ln) * 72 + 16 * c + 8 * hi];
            D = MFMA32(af, pb[c], D);
        }
        // staging: store tile i+1, prefetch tile i+2
        if (i + 1 < 8) {
            if (stK) tile_store72(Ks + (cur ^ 1) * 4608, tl, kA, kB);
            else if (stV) vt_store72(VT + (cur ^ 1) * 4608, tl, vA, vB);
            if (t < 64) cks[(cur ^ 1) * 64 + t] = ckr;
            if (i + 2 < 8) {
                const int st = st0 + i + 2;
                if (stK) tile_load<BF16>(K, xbase + (size_t)(st * 64) * ROWSTR, ROWSTR, tl, kA, kB);
                else if (stV) vt_load<BF16>(V, xbase + (size_t)(st * 64) * ROWSTR, tl, vA, vB);
                if (t < 64) ckr = cws[(size_t)nh * LL + st * 64 + t];
            }
        }
        // exp2 (c pre-scaled by log2e; varies with s = row)
        unsigned int pd[8];
        #pragma unroll
        for (int gIdx = 0; gIdx < 4; ++gIdx) {
            const float4 c4 = *(const float4*)&cc[32 * sstrip + 8 * gIdx + 4 * hi];
            const float ca[4] = {c4.x, c4.y, c4.z, c4.w};
            float f[4];
            #pragma unroll
            for (int b = 0; b < 4; ++b) {
                const float arg = fminf(fmaf(D[4 * gIdx + b], NORMC2, -ca[b]), 0.f);
                f[b] = fmaf(__builtin_amdgcn_exp2f(arg), RATIO, REPS);
            }
            pd[2 * gIdx] = pk2(f[0], f[1]);
            pd[2 * gIdx + 1] = pk2(f[2], f[3]);
        }
        // gemm2: akv[e][m] += V^T . F
        #pragma unroll
        for (int cp = 0; cp < 2; ++cp) {
            const short8 bf = xfrag(pd, cp, hi);
            const int scol = 32 * sstrip + 16 * cp + 8 * hi;
            const short8 v0 = *(const short8*)&Vc[ln * 72 + scol];
            const short8 v1 = *(const short8*)&Vc[(32 + ln) * 72 + scol];
            akv0 = MFMA32(v0, bf, akv0);
            akv1 = MFMA32(v1, bf, akv1);
            aks = MFMA32(ones, bf, aks);
        }
        wg_barrier_lds();
    }
    // epilogue: 4 epochs, each = one 64-m tile handled by its 4 waves via fin
    #pragma unroll 1
    for (int e4 = 0; e4 < 4; ++e4) {
        if (ep == e4) {
            const int slot = (w2 * 64 + (t & 63)) * 33;
            #pragma unroll
            for (int r = 0; r < 16; ++r) fin[slot + r] = akv0[r];
            #pragma unroll
            for (int r = 0; r < 16; ++r) fin[slot + 16 + r] = akv1[r];
            fin[slot + 32] = aks[0];
        }
        wg_barrier_lds();
        if (ep == e4) {
            const int tt = t & 255;
            const int mt = mtb * 4 + e4;
            const int e = tt >> 2;
            const int t16 = e >> 5, e5 = e & 31;
            const int hi_s = (e5 >> 2) & 1;
            const int reg = 16 * t16 + (e5 & 3) + 4 * (e5 >> 3);
            float* dst = kvf01 + (size_t)sp * KVSPLIT + (size_t)nh * (64 * MM)
                       + (size_t)e * MM + mt * 64 + (tt & 3) * 16;
            #pragma unroll
            for (int jq = 0; jq < 4; ++jq) {
                float o[4];
                #pragma unroll
                for (int b = 0; b < 4; ++b) {
                    const int m_local = (tt & 3) * 16 + 4 * jq + b;
                    const int ms = m_local >> 5;
                    const int lane_s = hi_s * 32 + (m_local & 31);
                    o[b] = fin[((2 * ms) * 64 + lane_s) * 33 + reg]
                         + fin[((2 * ms + 1) * 64 + lane_s) * 33 + reg];
                }
                *(float4*)&dst[4 * jq] = make_float4(o[0], o[1], o[2], o[3]);
            }
            if (tt < 64) {
                const int ms = tt >> 5;
                const float val = fin[((2 * ms) * 64 + (tt & 31)) * 33 + 32]
                                + fin[((2 * ms + 1) * 64 + (tt & 31)) * 33 + 32];
                ksum01[(size_t)sp * RSPLIT + (size_t)nh * MM + mt * 64 + tt] = val;
            }
        }
        wg_barrier_lds();
    }
}

__global__ __launch_bounds__(1024, 4) void LinearAttention_15985868276494_kv(
        const void* K, const void* V, const void* P, const float* flag,
        const float* cws, float* kvf01, float* ksum01) {
    extern __shared__ char smem_kv[];
    if (*flag != 0.f) kv_impl<true>(K, V, P, cws, kvf01, ksum01, smem_kv);
    else kv_impl<false>(K, V, P, cws, kvf01, ksum01, smem_kv);
}

// ---------------- reduce: kvT bf16 = sum of 4 splits; ksumW ----------------
__global__ __launch_bounds__(256) void LinearAttention_15985868276494_reduce(
        const float* __restrict__ kvf01, const float* __restrict__ ksum01,
        unsigned short* __restrict__ kvT, float* __restrict__ ksumW) {
    const int gid = blockIdx.x * 256 + threadIdx.x;
    const size_t i4 = (size_t)gid * 4;
    const float4 a = *(const float4*)&kvf01[i4];
    const float4 b = *(const float4*)&kvf01[KVSPLIT + i4];
    const float4 c = *(const float4*)&kvf01[2 * (size_t)KVSPLIT + i4];
    const float4 d = *(const float4*)&kvf01[3 * (size_t)KVSPLIT + i4];
    uint2 o;
    o.x = (unsigned)f2bf(a.x + b.x + c.x + d.x) | ((unsigned)f2bf(a.y + b.y + c.y + d.y) << 16);
    o.y = (unsigned)f2bf(a.z + b.z + c.z + d.z) | ((unsigned)f2bf(a.w + b.w + c.w + d.w) << 16);
    *(uint2*)&kvT[i4] = o;
    if (blockIdx.x < 32) {
        const float4 e = *(const float4*)&ksum01[i4];
        const float4 f = *(const float4*)&ksum01[RSPLIT + i4];
        const float4 g = *(const float4*)&ksum01[2 * RSPLIT + i4];
        const float4 h = *(const float4*)&ksum01[3 * RSPLIT + i4];
        *(float4*)&ksumW[i4] = make_float4(e.x + f.x + g.x + h.x, e.y + f.y + g.y + h.y,
                                           e.z + f.z + g.z + h.z, e.w + f.w + g.w + h.w);
    }
}

// ---------------- out (partial over m-quarter sp): po f32, pad f32 ----------------
// 512 blocks x 1024 thr, 2 blocks/CU. Block owns 256 l-rows; streams 8 m-tiles.
// LDS: Ps[2][4608] | KVs[2][4608] | kss[2][64]; fin aliases.
template <bool BF16>
__device__ void out_impl(const void* Q, const void* P, const float* cqw,
                         const unsigned short* kvT, const float* ksum,
                         float* po, float* pad, char* smem) {
    unsigned short* Ps = (unsigned short*)smem;              // [2][4608]
    unsigned short* KVs = (unsigned short*)(smem + 18432);   // [2][4608]
    unsigned short* kss = (unsigned short*)(smem + 36864);   // [2][64]
    float* fin = (float*)smem;                               // [4*64*33]

    const int t = threadIdx.x;
    const int w = t >> 6, ln = t & 31, hi = (t >> 5) & 1;
    const int w2 = w & 3, ep = w >> 2;
    const int mstrip = w2 & 1, lsub = w2 >> 1;
    const int lc = ep * 2 + lsub;  // 32-l chunk in [0,8)
    const int bid = blockIdx.x;
    const int xcd = bid & 7, rr = bid >> 3;
    const int gq = rr >> 3, lbb = rr & 7;
    const int g = gq * 8 + xcd;
    const int nh = g >> 2, sp = g & 3;
    const int n = nh >> 3, h = nh & 7;
    const size_t qbase = (size_t)n * (LL * ROWSTR) + (size_t)h * 64;
    const size_t kvbase = (size_t)nh * (size_t)(64 * MM);
    const int mt0 = sp * 8;
    const int lbase = lbb * 256;

    const bool stP = (t < 256), stKV = (t >= 256 && t < 512);
    const int tl = t & 255;

    // Q fragments direct from global (rows l = lbase + lc*32 + ln)
    short8 qb[4];
    #pragma unroll
    for (int c = 0; c < 4; ++c)
        qb[c] = row_load8<BF16>(Q, qbase + (size_t)(lbase + lc * 32 + ln) * ROWSTR, 16 * c + 8 * hi);
    const float cq = cqw[(size_t)nh * LL + lbase + lc * 32 + ln];

    uint4 pA, pB, kA, kB; float ksr = 0.f;
    if (stP) {
        tile_load<BF16>(P, (size_t)(mt0 * 64) * 64, 64, tl, pA, pB);
        tile_store72(Ps, tl, pA, pB);
        tile_load<BF16>(P, (size_t)((mt0 + 1) * 64) * 64, 64, tl, pA, pB);
    } else if (stKV) {
        tile_load<true>(kvT, kvbase + mt0 * 64, MM, tl, kA, kB);
        tile_store72(KVs, tl, kA, kB);
        tile_load<true>(kvT, kvbase + (mt0 + 1) * 64, MM, tl, kA, kB);
    }
    if (t < 64) {
        kss[t] = f2bf(ksum[(size_t)nh * MM + mt0 * 64 + t]);
        ksr = ksum[(size_t)nh * MM + (mt0 + 1) * 64 + t];
    }
    wg_barrier_lds();

    f32x16 ao0 = zero16(), ao1 = zero16(), ad = zero16();

    for (int i = 0; i < 8; ++i) {
        const int cur = i & 1;
        unsigned short* Pc = Ps + cur * 4608;
        unsigned short* Kc = KVs + cur * 4608;
        const unsigned short* ksc = kss + cur * 64;
        // gemm1: D[m][l] = P . Q^T
        f32x16 D = zero16();
        #pragma unroll
        for (int c = 0; c < 4; ++c) {
            const short8 af = *(const short8*)&Pc[(32 * mstrip + ln) * 72 + 16 * c + 8 * hi];
            D = MFMA32(af, qb[c], D);
        }
        // staging
        if (i + 1 < 8) {
            if (stP) tile_store72(Ps + (cur ^ 1) * 4608, tl, pA, pB);
            else if (stKV) tile_store72(KVs + (cur ^ 1) * 4608, tl, kA, kB);
            if (t < 64) kss[(cur ^ 1) * 64 + t] = f2bf(ksr);
            if (i + 2 < 8) {
                if (stP) tile_load<BF16>(P, (size_t)((mt0 + i + 2) * 64) * 64, 64, tl, pA, pB);
                else if (stKV) tile_load<true>(kvT, kvbase + (mt0 + i + 2) * 64, MM, tl, kA, kB);
                if (t < 64) ksr = ksum[(size_t)nh * MM + (mt0 + i + 2) * 64 + t];
            }
        }
        // exp2 (cq depends on l = col only)
        unsigned int pd[8];
        #pragma unroll
        for (int gIdx = 0; gIdx < 4; ++gIdx) {
            float f[4];
            #pragma unroll
            for (int b = 0; b < 4; ++b) {
                const float arg = fminf(fmaf(D[4 * gIdx + b], NORMC2, -cq), 0.f);
                f[b] = fmaf(__builtin_amdgcn_exp2f(arg), RATIO, REPS);
            }
            pd[2 * gIdx] = pk2(f[0], f[1]);
            pd[2 * gIdx + 1] = pk2(f[2], f[3]);
        }
        // gemm2: O[e][l] += KV . F ; ad[.][l] += ksum . F
        #pragma unroll
        for (int cp = 0; cp < 2; ++cp) {
            const short8 bf = xfrag(pd, cp, hi);
            const int mcol = 32 * mstrip + 16 * cp + 8 * hi;
            const short8 a0 = *(const short8*)&Kc[ln * 72 + mcol];
            const short8 a1 = *(const short8*)&Kc[(32 + ln) * 72 + mcol];
            const short8 k8 = *(const short8*)&ksc[mcol];
            ao0 = MFMA32(a0, bf, ao0);
            ao1 = MFMA32(a1, bf, ao1);
            ad = MFMA32(k8, bf, ad);
        }
        wg_barrier_lds();
    }
    // epilogue: 4 epochs, each = one 64-l tile
    #pragma unroll 1
    for (int e4 = 0; e4 < 4; ++e4) {
        if (ep == e4) {
            const int slot = (w2 * 64 + (t & 63)) * 33;
            #pragma unroll
            for (int r = 0; r < 16; ++r) fin[slot + r] = ao0[r];
            #pragma unroll
            for (int r = 0; r < 16; ++r) fin[slot + 16 + r] = ao1[r];
            fin[slot + 32] = ad[0];
        }
        wg_barrier_lds();
        if (ep == e4) {
            const int tt = t & 255;
            const int l_local = tt >> 2, eg = tt & 3;
            const int ls = l_local >> 5, lane_l = l_local & 31;
            const float adt = fin[((2 * ls) * 64 + lane_l) * 33 + 32]
                            + fin[((2 * ls + 1) * 64 + lane_l) * 33 + 32];
            const int l = (lbb * 4 + e4) * 64 + l_local;
            const size_t row = (size_t)(n * LL + l) * HH + h;
            if (eg == 0) pad[(size_t)sp * RSPLIT + row] = adt;
            float* dst = po + (size_t)sp * KVSPLIT + row * 64 + eg * 16;
            #pragma unroll
            for (int jq = 0; jq < 4; ++jq) {
                float o[4];
                #pragma unroll
                for (int b = 0; b < 4; ++b) {
                    const int e = eg * 16 + 4 * jq + b;
                    const int t16 = e >> 5, e5 = e & 31;
                    const int hi_s = (e5 >> 2) & 1;
                    const int reg = 16 * t16 + (e5 & 3) + 4 * (e5 >> 3);
                    const int lane_s = hi_s * 32 + lane_l;
                    o[b] = fin[((2 * ls) * 64 + lane_s) * 33 + reg]
                         + fin[((2 * ls + 1) * 64 + lane_s) * 33 + reg];
                }
                *(float4*)&dst[4 * jq] = make_float4(o[0], o[1], o[2], o[3]);
            }
        }
        wg_barrier_lds();
    }
}

__global__ __launch_bounds__(1024, 4) void LinearAttention_15985868276494_out(
        const void* Q, const void* P, const float* flag, const float* cqw,
        const unsigned short* kvT, const float* ksum, float* po, float* pad) {
    extern __shared__ char smem_out[];
    if (*flag != 0.f) out_impl<true>(Q, P, cqw, kvT, ksum, po, pad, smem_out);
    else out_impl<false>(Q, P, cqw, kvT, ksum, po, pad, smem_out);
}

// ---------------- out2: combine 4 m-quarters, normalize, emit ----------------
__global__ __launch_bounds__(256) void LinearAttention_15985868276494_out2(
        const float* __restrict__ po, const float* __restrict__ pad,
        const float* __restrict__ flag, void* __restrict__ outp) {
    const int gid = blockIdx.x * 256 + threadIdx.x;
    const int row = gid >> 2, eg = gid & 3;
    const float adt = pad[row] + pad[RSPLIT + row]
                    + pad[2 * RSPLIT + row] + pad[3 * RSPLIT + row];
    const float z = 1.0f / (adt + EPSD);
    const size_t base = (size_t)row * 64 + eg * 16;
    float vals[16];
    #pragma unroll
    for (int q4 = 0; q4 < 4; ++q4) {
        const float4 a = *(const float4*)&po[base + 4 * q4];
        const float4 b = *(const float4*)&po[KVSPLIT + base + 4 * q4];
        const float4 c = *(const float4*)&po[2 * (size_t)KVSPLIT + base + 4 * q4];
        const float4 d = *(const float4*)&po[3 * (size_t)KVSPLIT + base + 4 * q4];
        vals[4 * q4 + 0] = (a.x + b.x + c.x + d.x) * z;
        vals[4 * q4 + 1] = (a.y + b.y + c.y + d.y) * z;
        vals[4 * q4 + 2] = (a.z + b.z + c.z + d.z) * z;
        vals[4 * q4 + 3] = (a.w + b.w + c.w + d.w) * z;
    }
    if (*flag != 0.f) {
        uint4 o0, o1;
        o0.x = (unsigned)f2bf(vals[0]) | ((unsigned)f2bf(vals[1]) << 16);
        o0.y = (unsigned)f2bf(vals[2]) | ((unsigned)f2bf(vals[3]) << 16);
        o0.z = (unsigned)f2bf(vals[4]) | ((unsigned)f2bf(vals[5]) << 16);
        o0.w = (unsigned)f2bf(vals[6]) | ((unsigned)f2bf(vals[7]) << 16);
        o1.x = (unsigned)f2bf(vals[8]) | ((unsigned)f2bf(vals[9]) << 16);
        o1.y = (unsigned)f2bf(vals[10]) | ((unsigned)f2bf(vals[11]) << 16);
        o1.z = (unsigned)f2bf(vals[12]) | ((unsigned)f2bf(vals[13]) << 16);
        o1.w = (unsigned)f2bf(vals[14]) | ((unsigned)f2bf(vals[15]) << 16);
        unsigned short* op = (unsigned short*)outp + base;
        *(uint4*)op = o0;
        *(uint4*)(op + 8) = o1;
    } else {
        float* op = (float*)outp + base;
        #pragma unroll
        for (int q4 = 0; q4 < 4; ++q4)
            *(float4*)&op[4 * q4] = make_float4(vals[4 * q4], vals[4 * q4 + 1],
                                                vals[4 * q4 + 2], vals[4 * q4 + 3]);
    }
}

extern "C" void kernel_launch(void* const* d_in, const int* in_sizes, int n_in,
                              void* d_out, int out_size, void* d_ws, size_t ws_size,
                              hipStream_t stream) {
    const void* Q = d_in[0];
    const void* K = d_in[1];
    const void* V = d_in[2];
    const void* P = d_in[3];

    float* W = (float*)d_ws;
    float* flag = W;                                  // [16]
    float* c_k = W + 16;                              // [32768]
    float* c_q = c_k + 32768;                         // [32768]
    float* ksum01 = c_q + 32768;                      // [4][32768]; reused as pad
    float* kvf01 = ksum01 + 4 * RSPLIT;               // [4][16][64][2048] f32; reused as po
    float* ksumW = kvf01 + 4 * (size_t)KVSPLIT;       // [32768]
    unsigned short* kvTW = (unsigned short*)(ksumW + RSPLIT);  // [16][64][2048] bf16

    LinearAttention_15985868276494_detect<<<1, 64, 0, stream>>>(
        (const unsigned short*)P, flag);
    LinearAttention_15985868276494_stats<<<dim3(256, 2), 1024, 75776, stream>>>(
        K, Q, P, flag, c_k, c_q);
    LinearAttention_15985868276494_kv<<<dim3(512), 1024, 37376, stream>>>(
        K, V, P, flag, c_k, kvf01, ksum01);
    LinearAttention_15985868276494_reduce<<<2048, 256, 0, stream>>>(
        kvf01, ksum01, kvTW, ksumW);
    LinearAttention_15985868276494_out<<<dim3(512), 1024, 37120, stream>>>(
        Q, P, flag, c_q, kvTW, ksumW, kvf01, ksum01);
    LinearAttention_15985868276494_out2<<<512, 256, 0, stream>>>(
        kvf01, ksum01, flag, d_out);
}

// Round 9
// 192.849 us; speedup vs baseline: 4.8435x; 1.0998x over previous
//
#include <hip/hip_runtime.h>

// Performer linear attention, 32x32x16 MFMA, register-resident features.
// n=2, l=2048, h=8, e=64, m=2048. Dtype runtime-detected (bf16 confirmed).
// ws (floats): flag[16] | c_k[32768] | c_q[32768] | ksum01[4][32768] (reused as pad[4][32768])
//   | kvf01[4][16][64][2048] f32 (reused as po[4][32768][64]) | ksumW[32768] | kvT bf16[16][64][2048]
// R15: real-TLP round. R14 proved 1024-thr blocks cap at 1 blk/CU: unified VGPR+AGPR
//     (64+48=112) rounds to the 128 allocation class -> 16 waves/CU (R13's 48-reg build
//     DID get 2 blks/73% occ). Fix: 512-thr blocks (8 waves) at same per-wave regs ->
//     2 independent barrier domains/CU within the 16-wave budget (LDS 37.4KBx2=74.8KB).
//     Each wave folds sstrip/mstrip: two independent sub-chains per iter (intra-wave ILP,
//     R12's goal without the spill). kv: aks MFMA -> f32 scalar sum (+shfl); kv fin
//     epilogue deleted (direct half-wave-contiguous stores; kills the 1.57M conflicts).
//     out keeps 2-epoch fin transpose. stats/reduce/out2 unchanged from R14.

#define LL 2048
#define HH 8
#define MM 2048
#define ROWSTR 512  // HH*64

#define NORMC 0.35355339059327373f   // 64^-0.25
#define LOG2E 1.4426950408889634f
#define NORMC2 (NORMC * LOG2E)
#define RATIO 0.022097086912079608f  // 2048^-0.5
#define KEPS 1e-4f
#define REPS (RATIO * KEPS)
#define EPSD 1e-6f

#define KVSPLIT 2097152
#define RSPLIT 32768

typedef __attribute__((ext_vector_type(8))) short short8;
typedef __attribute__((ext_vector_type(16))) float f32x16;

#define MFMA32(a, b, c) __builtin_amdgcn_mfma_f32_32x32x16_bf16((a), (b), (c), 0, 0, 0)

// LDS-only workgroup barrier: drains lgkmcnt but leaves global loads in flight.
__device__ __forceinline__ void wg_barrier_lds() {
    asm volatile("s_waitcnt lgkmcnt(0)" ::: "memory");
    __builtin_amdgcn_s_barrier();
    __builtin_amdgcn_sched_barrier(0);
}

__device__ __forceinline__ f32x16 zero16() {
    f32x16 v;
    #pragma unroll
    for (int i = 0; i < 16; ++i) v[i] = 0.f;
    return v;
}
__device__ __forceinline__ unsigned short f2bf(float f) {  // RNE
    union { float f; unsigned int u; } v; v.f = f;
    unsigned int r = v.u + 0x7fffu + ((v.u >> 16) & 1u);
    return (unsigned short)(r >> 16);
}
__device__ __forceinline__ unsigned int pk2(float lo, float hi) {  // trunc pack
    return __builtin_amdgcn_perm(__float_as_uint(hi), __float_as_uint(lo), 0x07060302u);
}
__device__ __forceinline__ float bf2f(unsigned short u) {
    union { unsigned int ui; float f; } v; v.ui = ((unsigned int)u) << 16; return v.f;
}

// ---- direct global row-fragment load: 8 bf16 at row*stride + off ----
template <bool BF16>
__device__ __forceinline__ short8 row_load8(const void* src, size_t rowbase, int off) {
    if (BF16) {
        return *(const short8*)((const unsigned short*)src + rowbase + off);
    } else {
        const float* p = (const float*)src + rowbase + off;
        float4 f0 = ((const float4*)p)[0], f1 = ((const float4*)p)[1];
        union { unsigned int u[4]; short8 s; } v;
        v.u[0] = pk2(f0.x, f0.y); v.u[1] = pk2(f0.z, f0.w);
        v.u[2] = pk2(f1.x, f1.y); v.u[3] = pk2(f1.z, f1.w);
        return v.s;
    }
}

// ---- 64x64 tile staging into LDS [64][72] bf16 (256-thread pattern) ----
template <bool BF16>
__device__ __forceinline__ void tile_load(const void* src, size_t base, size_t rstride,
                                          int t, uint4& A, uint4& B) {
    const int row = t >> 2, c16 = (t & 3) * 16;
    if (BF16) {
        const unsigned short* p = (const unsigned short*)src + base + (size_t)row * rstride + c16;
        A = *(const uint4*)p;
        B = *(const uint4*)(p + 8);
    } else {
        const float* p = (const float*)src + base + (size_t)row * rstride + c16;
        float4 f0 = ((const float4*)p)[0], f1 = ((const float4*)p)[1];
        float4 f2 = ((const float4*)p)[2], f3 = ((const float4*)p)[3];
        A.x = pk2(f0.x, f0.y); A.y = pk2(f0.z, f0.w);
        A.z = pk2(f1.x, f1.y); A.w = pk2(f1.z, f1.w);
        B.x = pk2(f2.x, f2.y); B.y = pk2(f2.z, f2.w);
        B.z = pk2(f3.x, f3.y); B.w = pk2(f3.z, f3.w);
    }
}
__device__ __forceinline__ void tile_store72(unsigned short* D, int t, uint4 A, uint4 B) {
    const int row = t >> 2, c16 = (t & 3) * 16;
    *(uint4*)&D[row * 72 + c16] = A;
    *(uint4*)&D[row * 72 + c16 + 8] = B;
}

// ---- V transpose staging into LDS [64e][72] (256-thread pattern) ----
template <bool BF16>
__device__ __forceinline__ void vt_load(const void* V, size_t base, int t, uint4& A, uint4& B) {
    const int s0 = (t & 31) * 2, e0 = (t >> 5) * 8;
    if (BF16) {
        const unsigned short* p = (const unsigned short*)V + base + (size_t)s0 * ROWSTR + e0;
        A = *(const uint4*)p;
        B = *(const uint4*)(p + ROWSTR);
    } else {
        const float* p = (const float*)V + base + (size_t)s0 * ROWSTR + e0;
        float4 f0 = ((const float4*)p)[0], f1 = ((const float4*)p)[1];
        const float* q = p + ROWSTR;
        float4 g0 = ((const float4*)q)[0], g1 = ((const float4*)q)[1];
        A.x = pk2(f0.x, f0.y); A.y = pk2(f0.z, f0.w);
        A.z = pk2(f1.x, f1.y); A.w = pk2(f1.z, f1.w);
        B.x = pk2(g0.x, g0.y); B.y = pk2(g0.z, g0.w);
        B.z = pk2(g1.x, g1.y); B.w = pk2(g1.z, g1.w);
    }
}
__device__ __forceinline__ void vt_store72(unsigned short* VT, int t, uint4 A, uint4 B) {
    const int s0 = (t & 31) * 2, e0 = (t >> 5) * 8;
    const unsigned ua[4] = {A.x, A.y, A.z, A.w}, ub[4] = {B.x, B.y, B.z, B.w};
    #pragma unroll
    for (int i = 0; i < 4; ++i) {
        *(unsigned*)&VT[(e0 + 2 * i) * 72 + s0] = (ua[i] & 0xFFFFu) | (ub[i] << 16);
        *(unsigned*)&VT[(e0 + 2 * i + 1) * 72 + s0] = (ua[i] >> 16) | (ub[i] & 0xFFFF0000u);
    }
}

// ---- D-layout -> B-operand exchange (half-wave) ----
__device__ __forceinline__ short8 xfrag(const unsigned int pd[8], int cp, int hi) {
    const unsigned int s0 = hi ? pd[4 * cp + 0] : pd[4 * cp + 2];
    const unsigned int s1 = hi ? pd[4 * cp + 1] : pd[4 * cp + 3];
    const unsigned int r0 = (unsigned int)__shfl_xor((int)s0, 32);
    const unsigned int r1 = (unsigned int)__shfl_xor((int)s1, 32);
    union { unsigned int u[4]; short8 s; } v;
    v.u[0] = hi ? r0 : pd[4 * cp + 0];
    v.u[1] = hi ? r1 : pd[4 * cp + 1];
    v.u[2] = hi ? pd[4 * cp + 2] : r0;
    v.u[3] = hi ? pd[4 * cp + 3] : r1;
    return v.s;
}

// ---------------- dtype detection ----------------
__global__ void LinearAttention_15985868276494_detect(const unsigned short* __restrict__ P,
                                                      float* __restrict__ flag) {
    if (threadIdx.x == 0) {
        int sane = 1;
        #pragma unroll
        for (int i = 0; i < 16; ++i) {
            const unsigned e = (P[2 * i] >> 7) & 0xFF;
            if (e < 101 || e > 141) sane = 0;
        }
        *flag = sane ? 1.0f : 0.0f;
    }
}

// ---------------- stats: c[nh][l]*log2e, 128 rows/block, 8 iters x 4 P-tiles ----------------
// (unchanged from R14)
template <bool BF16>
__device__ void stats_impl(const void* X, const void* P, float* cws, char* smem) {
    unsigned short* Ps = (unsigned short*)smem;        // [2][4][4608 shorts]
    float* red = (float*)(smem + 73728);               // [512]
    const int t = threadIdx.x;
    const int w = t >> 6, ln = t & 31, hi = (t >> 5) & 1;
    const int mstrip = w & 1, r3 = (w >> 1) & 3, tsel = w >> 3;
    const int grp = w >> 2, tl = t & 255;
    const int row_base = blockIdx.x * 128;

    short8 xb[4];
    #pragma unroll
    for (int c = 0; c < 4; ++c)
        xb[c] = row_load8<BF16>(X, (size_t)(row_base + r3 * 32 + ln) * 64, 16 * c + 8 * hi);

    uint4 pA, pB;
    {
        uint4 a0, b0;
        tile_load<BF16>(P, (size_t)(grp * 64) * 64, 64, tl, a0, b0);
        tile_store72(Ps + grp * 4608, tl, a0, b0);
        tile_load<BF16>(P, (size_t)((4 + grp) * 64) * 64, 64, tl, pA, pB);
    }
    wg_barrier_lds();

    float rmax = -3e38f;
    for (int i = 0; i < 8; ++i) {
        const int cur = i & 1;
        unsigned short* Pq = Ps + cur * 18432;
        #pragma unroll
        for (int j = 0; j < 2; ++j) {
            unsigned short* Pc = Pq + (tsel * 2 + j) * 4608;
            f32x16 acc = zero16();
            #pragma unroll
            for (int c = 0; c < 4; ++c) {
                const short8 af = *(const short8*)&Pc[(32 * mstrip + ln) * 72 + 16 * c + 8 * hi];
                acc = MFMA32(af, xb[c], acc);
            }
            #pragma unroll
            for (int r = 0; r < 16; ++r) rmax = fmaxf(rmax, acc[r]);
            if (j == 0 && i + 1 < 8) {
                tile_store72(Ps + (cur ^ 1) * 18432 + grp * 4608, tl, pA, pB);
                if (i + 2 < 8)
                    tile_load<BF16>(P, (size_t)(((i + 2) * 4 + grp) * 64) * 64, 64, tl, pA, pB);
            }
        }
        wg_barrier_lds();
    }
    rmax = fmaxf(rmax, __shfl_xor(rmax, 32));
    if (hi == 0) red[w * 32 + ln] = rmax;
    float s2 = 0.f;
    if (mstrip == 0 && tsel == 0) {
        #pragma unroll
        for (int c = 0; c < 4; ++c) {
            union { short8 s; unsigned int u[4]; } uv; uv.s = xb[c];
            #pragma unroll
            for (int i2 = 0; i2 < 4; ++i2) {
                const float lo = bf2f((unsigned short)(uv.u[i2] & 0xFFFF));
                const float hv = bf2f((unsigned short)(uv.u[i2] >> 16));
                s2 = fmaf(lo, lo, s2); s2 = fmaf(hv, hv, s2);
            }
        }
        s2 += __shfl_xor(s2, 32);
    }
    wg_barrier_lds();
    if (mstrip == 0 && tsel == 0 && hi == 0) {
        const float rm = fmaxf(fmaxf(red[(r3 * 2) * 32 + ln], red[(r3 * 2 + 1) * 32 + ln]),
                               fmaxf(red[(8 + r3 * 2) * 32 + ln], red[(8 + r3 * 2 + 1) * 32 + ln]));
        const int rg = row_base + r3 * 32 + ln;
        const int n = rg >> 14, l = (rg >> 3) & 2047, h = rg & 7;
        cws[(size_t)((n << 3) | h) * LL + l] =
            (NORMC * rm + (0.5f * NORMC * NORMC) * s2) * LOG2E;
    }
}

__global__ __launch_bounds__(1024, 4) void LinearAttention_15985868276494_stats(
        const void* K, const void* Q, const void* P, const float* flag,
        float* c_k, float* c_q) {
    extern __shared__ char smem_st[];
    const void* X = (blockIdx.y == 0) ? K : Q;
    float* cws = (blockIdx.y == 0) ? c_k : c_q;
    if (*flag != 0.f) stats_impl<true>(X, P, cws, smem_st);
    else stats_impl<false>(X, P, cws, smem_st);
}

// ---------------- kv: partial kvf[sp][nh][e][m] f32, ksum01 (sp in 0..3) ----------------
// 512 blocks x 512 thr (8 waves), 2 blocks/CU. Block owns 256 m-cols (wave w owns mc=w);
// streams 8 K/V s-tiles; each wave processes BOTH sstrips per iter (2 indep sub-chains).
// Decode: g=gq*8+xcd, nh=g>>2, sp=g&3; 8 mtb-blocks/group on 1 XCD (8-way multicast).
// ksum via per-lane f32 sum (+shfl), no aks MFMA; epilogue = direct contiguous stores.
// LDS: Ks[2][4608] | VT[2][4608] | cks[2][64]  (37376 B; x2 blocks = 74.8KB < 160KB).
template <bool BF16>
__device__ void kv_impl(const void* K, const void* V, const void* P, const float* cws,
                        float* kvf01, float* ksum01, char* smem) {
    unsigned short* Ks = (unsigned short*)smem;            // [2][4608]
    unsigned short* VT = (unsigned short*)(smem + 18432);  // [2][4608]
    float* cks = (float*)(smem + 36864);                   // [2][64]

    const int t = threadIdx.x;
    const int w = t >> 6, ln = t & 31, hi = (t >> 5) & 1;
    const int mc = w;  // 32-m chunk in [0,8)
    const int bid = blockIdx.x;
    const int xcd = bid & 7, rr = bid >> 3;
    const int gq = rr >> 3, mtb = rr & 7;
    const int g = gq * 8 + xcd;
    const int nh = g >> 2, sp = g & 3;
    const int n = nh >> 3, h = nh & 7;
    const size_t xbase = (size_t)n * (LL * ROWSTR) + (size_t)h * 64;
    const int st0 = sp * 8;
    const int mbase = mtb * 256;

    const bool stK = (t < 256);
    const int tl = t & 255;

    // P fragments direct from global (rows m = mbase + mc*32 + ln)
    short8 pb[4];
    #pragma unroll
    for (int c = 0; c < 4; ++c)
        pb[c] = row_load8<BF16>(P, (size_t)(mbase + mc * 32 + ln) * 64, 16 * c + 8 * hi);

    uint4 kA, kB, vA, vB; float ckr = 0.f;
    if (stK) {
        tile_load<BF16>(K, xbase + (size_t)(st0 * 64) * ROWSTR, ROWSTR, tl, kA, kB);
        tile_store72(Ks, tl, kA, kB);
        tile_load<BF16>(K, xbase + (size_t)((st0 + 1) * 64) * ROWSTR, ROWSTR, tl, kA, kB);
    } else {
        vt_load<BF16>(V, xbase + (size_t)(st0 * 64) * ROWSTR, tl, vA, vB);
        vt_store72(VT, tl, vA, vB);
        vt_load<BF16>(V, xbase + (size_t)((st0 + 1) * 64) * ROWSTR, tl, vA, vB);
    }
    if (t < 64) {
        cks[t] = cws[(size_t)nh * LL + st0 * 64 + t];
        ckr = cws[(size_t)nh * LL + (st0 + 1) * 64 + t];
    }
    wg_barrier_lds();

    f32x16 akv0 = zero16(), akv1 = zero16();
    float ks = 0.f;

    for (int i = 0; i < 8; ++i) {
        const int cur = i & 1;
        unsigned short* Kc = Ks + cur * 4608;
        unsigned short* Vc = VT + cur * 4608;
        const float* cc = cks + cur * 64;
        #pragma unroll
        for (int ss = 0; ss < 2; ++ss) {
            // gemm1: D[s][m] for this sstrip
            f32x16 D = zero16();
            #pragma unroll
            for (int c = 0; c < 4; ++c) {
                const short8 af = *(const short8*)&Kc[(32 * ss + ln) * 72 + 16 * c + 8 * hi];
                D = MFMA32(af, pb[c], D);
            }
            // staging once per iter, after first gemm1 (vmcnt wait overlaps compute)
            if (ss == 0 && i + 1 < 8) {
                if (stK) tile_store72(Ks + (cur ^ 1) * 4608, tl, kA, kB);
                else vt_store72(VT + (cur ^ 1) * 4608, tl, vA, vB);
                if (t < 64) cks[(cur ^ 1) * 64 + t] = ckr;
                if (i + 2 < 8) {
                    const int st = st0 + i + 2;
                    if (stK) tile_load<BF16>(K, xbase + (size_t)(st * 64) * ROWSTR, ROWSTR, tl, kA, kB);
                    else vt_load<BF16>(V, xbase + (size_t)(st * 64) * ROWSTR, tl, vA, vB);
                    if (t < 64) ckr = cws[(size_t)nh * LL + st * 64 + t];
                }
            }
            // exp2 + per-lane ksum partial
            unsigned int pd[8];
            #pragma unroll
            for (int gIdx = 0; gIdx < 4; ++gIdx) {
                const float4 c4 = *(const float4*)&cc[32 * ss + 8 * gIdx + 4 * hi];
                const float ca[4] = {c4.x, c4.y, c4.z, c4.w};
                float f[4];
                #pragma unroll
                for (int b = 0; b < 4; ++b) {
                    const float arg = fminf(fmaf(D[4 * gIdx + b], NORMC2, -ca[b]), 0.f);
                    f[b] = fmaf(__builtin_amdgcn_exp2f(arg), RATIO, REPS);
                }
                ks += (f[0] + f[1]) + (f[2] + f[3]);
                pd[2 * gIdx] = pk2(f[0], f[1]);
                pd[2 * gIdx + 1] = pk2(f[2], f[3]);
            }
            // gemm2: akv[e][m] += V^T . F
            #pragma unroll
            for (int cp = 0; cp < 2; ++cp) {
                const short8 bf = xfrag(pd, cp, hi);
                const int scol = 32 * ss + 16 * cp + 8 * hi;
                const short8 v0 = *(const short8*)&Vc[ln * 72 + scol];
                const short8 v1 = *(const short8*)&Vc[(32 + ln) * 72 + scol];
                akv0 = MFMA32(v0, bf, akv0);
                akv1 = MFMA32(v1, bf, akv1);
            }
        }
        wg_barrier_lds();
    }
    // epilogue: direct stores (half-wave contiguous 128B per segment), ksum via shfl
    {
        ks += __shfl_xor(ks, 32);
        const int m = mbase + mc * 32 + ln;
        if (hi == 0)
            ksum01[(size_t)sp * RSPLIT + (size_t)nh * MM + m] = ks;
        float* basep = kvf01 + (size_t)sp * KVSPLIT + (size_t)nh * (size_t)(64 * MM) + m;
        #pragma unroll
        for (int r = 0; r < 16; ++r) {
            const int e = (r & 3) + 8 * (r >> 2) + 4 * hi;
            basep[(size_t)e * MM] = akv0[r];
            basep[(size_t)(e + 32) * MM] = akv1[r];
        }
    }
}

__global__ __launch_bounds__(512, 4) void LinearAttention_15985868276494_kv(
        const void* K, const void* V, const void* P, const float* flag,
        const float* cws, float* kvf01, float* ksum01) {
    extern __shared__ char smem_kv[];
    if (*flag != 0.f) kv_impl<true>(K, V, P, cws, kvf01, ksum01, smem_kv);
    else kv_impl<false>(K, V, P, cws, kvf01, ksum01, smem_kv);
}

// ---------------- reduce: kvT bf16 = sum of 4 splits; ksumW ----------------
__global__ __launch_bounds__(256) void LinearAttention_15985868276494_reduce(
        const float* __restrict__ kvf01, const float* __restrict__ ksum01,
        unsigned short* __restrict__ kvT, float* __restrict__ ksumW) {
    const int gid = blockIdx.x * 256 + threadIdx.x;
    const size_t i4 = (size_t)gid * 4;
    const float4 a = *(const float4*)&kvf01[i4];
    const float4 b = *(const float4*)&kvf01[KVSPLIT + i4];
    const float4 c = *(const float4*)&kvf01[2 * (size_t)KVSPLIT + i4];
    const float4 d = *(const float4*)&kvf01[3 * (size_t)KVSPLIT + i4];
    uint2 o;
    o.x = (unsigned)f2bf(a.x + b.x + c.x + d.x) | ((unsigned)f2bf(a.y + b.y + c.y + d.y) << 16);
    o.y = (unsigned)f2bf(a.z + b.z + c.z + d.z) | ((unsigned)f2bf(a.w + b.w + c.w + d.w) << 16);
    *(uint2*)&kvT[i4] = o;
    if (blockIdx.x < 32) {
        const float4 e = *(const float4*)&ksum01[i4];
        const float4 f = *(const float4*)&ksum01[RSPLIT + i4];
        const float4 g = *(const float4*)&ksum01[2 * RSPLIT + i4];
        const float4 h = *(const float4*)&ksum01[3 * RSPLIT + i4];
        *(float4*)&ksumW[i4] = make_float4(e.x + f.x + g.x + h.x, e.y + f.y + g.y + h.y,
                                           e.z + f.z + g.z + h.z, e.w + f.w + g.w + h.w);
    }
}

// ---------------- out (partial over m-quarter sp): po f32, pad f32 ----------------
// 512 blocks x 512 thr (8 waves), 2 blocks/CU. Block owns 256 l-rows (wave w owns lc=w);
// streams 8 m-tiles; each wave processes BOTH mstrips per iter. Epilogue: 2-epoch fin
// transpose (fin[4*64*33] f32 = 33.8KB aliases Ps+KVs region).
// LDS: Ps[2][4608] | KVs[2][4608] | kss[2][64] (37120 B).
template <bool BF16>
__device__ void out_impl(const void* Q, const void* P, const float* cqw,
                         const unsigned short* kvT, const float* ksum,
                         float* po, float* pad, char* smem) {
    unsigned short* Ps = (unsigned short*)smem;              // [2][4608]
    unsigned short* KVs = (unsigned short*)(smem + 18432);   // [2][4608]
    unsigned short* kss = (unsigned short*)(smem + 36864);   // [2][64]
    float* fin = (float*)smem;                               // [4*64*33]

    const int t = threadIdx.x;
    const int w = t >> 6, ln = t & 31, hi = (t >> 5) & 1;
    const int lc = w;  // 32-l chunk in [0,8)
    const int bid = blockIdx.x;
    const int xcd = bid & 7, rr = bid >> 3;
    const int gq = rr >> 3, lbb = rr & 7;
    const int g = gq * 8 + xcd;
    const int nh = g >> 2, sp = g & 3;
    const int n = nh >> 3, h = nh & 7;
    const size_t qbase = (size_t)n * (LL * ROWSTR) + (size_t)h * 64;
    const size_t kvbase = (size_t)nh * (size_t)(64 * MM);
    const int mt0 = sp * 8;
    const int lbase = lbb * 256;

    const bool stP = (t < 256);
    const int tl = t & 255;

    // Q fragments direct from global (rows l = lbase + lc*32 + ln)
    short8 qb[4];
    #pragma unroll
    for (int c = 0; c < 4; ++c)
        qb[c] = row_load8<BF16>(Q, qbase + (size_t)(lbase + lc * 32 + ln) * ROWSTR, 16 * c + 8 * hi);
    const float cq = cqw[(size_t)nh * LL + lbase + lc * 32 + ln];

    uint4 pA, pB, kA, kB; float ksr = 0.f;
    if (stP) {
        tile_load<BF16>(P, (size_t)(mt0 * 64) * 64, 64, tl, pA, pB);
        tile_store72(Ps, tl, pA, pB);
        tile_load<BF16>(P, (size_t)((mt0 + 1) * 64) * 64, 64, tl, pA, pB);
    } else {
        tile_load<true>(kvT, kvbase + mt0 * 64, MM, tl, kA, kB);
        tile_store72(KVs, tl, kA, kB);
        tile_load<true>(kvT, kvbase + (mt0 + 1) * 64, MM, tl, kA, kB);
    }
    if (t < 64) {
        kss[t] = f2bf(ksum[(size_t)nh * MM + mt0 * 64 + t]);
        ksr = ksum[(size_t)nh * MM + (mt0 + 1) * 64 + t];
    }
    wg_barrier_lds();

    f32x16 ao0 = zero16(), ao1 = zero16(), ad = zero16();

    for (int i = 0; i < 8; ++i) {
        const int cur = i & 1;
        unsigned short* Pc = Ps + cur * 4608;
        unsigned short* Kc = KVs + cur * 4608;
        const unsigned short* ksc = kss + cur * 64;
        #pragma unroll
        for (int ms = 0; ms < 2; ++ms) {
            // gemm1: D[m][l] for this mstrip
            f32x16 D = zero16();
            #pragma unroll
            for (int c = 0; c < 4; ++c) {
                const short8 af = *(const short8*)&Pc[(32 * ms + ln) * 72 + 16 * c + 8 * hi];
                D = MFMA32(af, qb[c], D);
            }
            if (ms == 0 && i + 1 < 8) {
                if (stP) tile_store72(Ps + (cur ^ 1) * 4608, tl, pA, pB);
                else tile_store72(KVs + (cur ^ 1) * 4608, tl, kA, kB);
                if (t < 64) kss[(cur ^ 1) * 64 + t] = f2bf(ksr);
                if (i + 2 < 8) {
                    if (stP) tile_load<BF16>(P, (size_t)((mt0 + i + 2) * 64) * 64, 64, tl, pA, pB);
                    else tile_load<true>(kvT, kvbase + (mt0 + i + 2) * 64, MM, tl, kA, kB);
                    if (t < 64) ksr = ksum[(size_t)nh * MM + (mt0 + i + 2) * 64 + t];
                }
            }
            // exp2 (cq depends on l = col only)
            unsigned int pd[8];
            #pragma unroll
            for (int gIdx = 0; gIdx < 4; ++gIdx) {
                float f[4];
                #pragma unroll
                for (int b = 0; b < 4; ++b) {
                    const float arg = fminf(fmaf(D[4 * gIdx + b], NORMC2, -cq), 0.f);
                    f[b] = fmaf(__builtin_amdgcn_exp2f(arg), RATIO, REPS);
                }
                pd[2 * gIdx] = pk2(f[0], f[1]);
                pd[2 * gIdx + 1] = pk2(f[2], f[3]);
            }
            // gemm2: O[e][l] += KV . F ; ad[.][l] += ksum . F
            #pragma unroll
            for (int cp = 0; cp < 2; ++cp) {
                const short8 bf = xfrag(pd, cp, hi);
                const int mcol = 32 * ms + 16 * cp + 8 * hi;
                const short8 a0 = *(const short8*)&Kc[ln * 72 + mcol];
                const short8 a1 = *(const short8*)&Kc[(32 + ln) * 72 + mcol];
                const short8 k8 = *(const short8*)&ksc[mcol];
                ao0 = MFMA32(a0, bf, ao0);
                ao1 = MFMA32(a1, bf, ao1);
                ad = MFMA32(k8, bf, ad);
            }
        }
        wg_barrier_lds();
    }
    // epilogue: 2 epochs of 4 waves; fin transpose for coalesced po writes
    #pragma unroll 1
    for (int e2 = 0; e2 < 2; ++e2) {
        if ((w >> 2) == e2) {
            const int slot = ((w & 3) * 64 + (t & 63)) * 33;
            #pragma unroll
            for (int r = 0; r < 16; ++r) fin[slot + r] = ao0[r];
            #pragma unroll
            for (int r = 0; r < 16; ++r) fin[slot + 16 + r] = ao1[r];
            fin[slot + 32] = ad[0];
        }
        wg_barrier_lds();
        {
            // all 512 threads read this epoch's 128 l-rows x 64 e
            const int l128 = t >> 2, eg = t & 3;
            const int w2 = l128 >> 5, lane_l = l128 & 31;
            const float adt = fin[(w2 * 64 + lane_l) * 33 + 32];
            const int l = lbase + (e2 * 4 + w2) * 32 + lane_l;
            const size_t row = (size_t)(n * LL + l) * HH + h;
            if (eg == 0) pad[(size_t)sp * RSPLIT + row] = adt;
            float* dst = po + (size_t)sp * KVSPLIT + row * 64 + eg * 16;
            #pragma unroll
            for (int jq = 0; jq < 4; ++jq) {
                float o[4];
                #pragma unroll
                for (int b = 0; b < 4; ++b) {
                    const int e = eg * 16 + 4 * jq + b;
                    const int t16 = e >> 5, e5 = e & 31;
                    const int hi_s = (e5 >> 2) & 1;
                    const int reg = 16 * t16 + (e5 & 3) + 4 * (e5 >> 3);
                    const int lane_s = hi_s * 32 + lane_l;
                    o[b] = fin[(w2 * 64 + lane_s) * 33 + reg];
                }
                *(float4*)&dst[4 * jq] = make_float4(o[0], o[1], o[2], o[3]);
            }
        }
        wg_barrier_lds();
    }
}

__global__ __launch_bounds__(512, 4) void LinearAttention_15985868276494_out(
        const void* Q, const void* P, const float* flag, const float* cqw,
        const unsigned short* kvT, const float* ksum, float* po, float* pad) {
    extern __shared__ char smem_out[];
    if (*flag != 0.f) out_impl<true>(Q, P, cqw, kvT, ksum, po, pad, smem_out);
    else out_impl<false>(Q, P, cqw, kvT, ksum, po, pad, smem_out);
}

// ---------------- out2: combine 4 m-quarters, normalize, emit ----------------
__global__ __launch_bounds__(256) void LinearAttention_15985868276494_out2(
        const float* __restrict__ po, const float* __restrict__ pad,
        const float* __restrict__ flag, void* __restrict__ outp) {
    const int gid = blockIdx.x * 256 + threadIdx.x;
    const int row = gid >> 2, eg = gid & 3;
    const float adt = pad[row] + pad[RSPLIT + row]
                    + pad[2 * RSPLIT + row] + pad[3 * RSPLIT + row];
    const float z = 1.0f / (adt + EPSD);
    const size_t base = (size_t)row * 64 + eg * 16;
    float vals[16];
    #pragma unroll
    for (int q4 = 0; q4 < 4; ++q4) {
        const float4 a = *(const float4*)&po[base + 4 * q4];
        const float4 b = *(const float4*)&po[KVSPLIT + base + 4 * q4];
        const float4 c = *(const float4*)&po[2 * (size_t)KVSPLIT + base + 4 * q4];
        const float4 d = *(const float4*)&po[3 * (size_t)KVSPLIT + base + 4 * q4];
        vals[4 * q4 + 0] = (a.x + b.x + c.x + d.x) * z;
        vals[4 * q4 + 1] = (a.y + b.y + c.y + d.y) * z;
        vals[4 * q4 + 2] = (a.z + b.z + c.z + d.z) * z;
        vals[4 * q4 + 3] = (a.w + b.w + c.w + d.w) * z;
    }
    if (*flag != 0.f) {
        uint4 o0, o1;
        o0.x = (unsigned)f2bf(vals[0]) | ((unsigned)f2bf(vals[1]) << 16);
        o0.y = (unsigned)f2bf(vals[2]) | ((unsigned)f2bf(vals[3]) << 16);
        o0.z = (unsigned)f2bf(vals[4]) | ((unsigned)f2bf(vals[5]) << 16);
        o0.w = (unsigned)f2bf(vals[6]) | ((unsigned)f2bf(vals[7]) << 16);
        o1.x = (unsigned)f2bf(vals[8]) | ((unsigned)f2bf(vals[9]) << 16);
        o1.y = (unsigned)f2bf(vals[10]) | ((unsigned)f2bf(vals[11]) << 16);
        o1.z = (unsigned)f2bf(vals[12]) | ((unsigned)f2bf(vals[13]) << 16);
        o1.w = (unsigned)f2bf(vals[14]) | ((unsigned)f2bf(vals[15]) << 16);
        unsigned short* op = (unsigned short*)outp + base;
        *(uint4*)op = o0;
        *(uint4*)(op + 8) = o1;
    } else {
        float* op = (float*)outp + base;
        #pragma unroll
        for (int q4 = 0; q4 < 4; ++q4)
            *(float4*)&op[4 * q4] = make_float4(vals[4 * q4], vals[4 * q4 + 1],
                                                vals[4 * q4 + 2], vals[4 * q4 + 3]);
    }
}

extern "C" void kernel_launch(void* const* d_in, const int* in_sizes, int n_in,
                              void* d_out, int out_size, void* d_ws, size_t ws_size,
                              hipStream_t stream) {
    const void* Q = d_in[0];
    const void* K = d_in[1];
    const void* V = d_in[2];
    const void* P = d_in[3];

    float* W = (float*)d_ws;
    float* flag = W;                                  // [16]
    float* c_k = W + 16;                              // [32768]
    float* c_q = c_k + 32768;                         // [32768]
    float* ksum01 = c_q + 32768;                      // [4][32768]; reused as pad
    float* kvf01 = ksum01 + 4 * RSPLIT;               // [4][16][64][2048] f32; reused as po
    float* ksumW = kvf01 + 4 * (size_t)KVSPLIT;       // [32768]
    unsigned short* kvTW = (unsigned short*)(ksumW + RSPLIT);  // [16][64][2048] bf16

    LinearAttention_15985868276494_detect<<<1, 64, 0, stream>>>(
        (const unsigned short*)P, flag);
    LinearAttention_15985868276494_stats<<<dim3(256, 2), 1024, 75776, stream>>>(
        K, Q, P, flag, c_k, c_q);
    LinearAttention_15985868276494_kv<<<dim3(512), 512, 37376, stream>>>(
        K, V, P, flag, c_k, kvf01, ksum01);
    LinearAttention_15985868276494_reduce<<<2048, 256, 0, stream>>>(
        kvf01, ksum01, kvTW, ksumW);
    LinearAttention_15985868276494_out<<<dim3(512), 512, 37120, stream>>>(
        Q, P, flag, c_q, kvTW, ksumW, kvf01, ksum01);
    LinearAttention_15985868276494_out2<<<512, 256, 0, stream>>>(
        kvf01, ksum01, flag, d_out);
}

// Round 10
// 185.434 us; speedup vs baseline: 5.0372x; 1.0400x over previous
//
#include <hip/hip_runtime.h>

// Performer linear attention, 32x32x16 MFMA, register-resident features.
// n=2, l=2048, h=8, e=64, m=2048. Dtype runtime-detected (bf16 confirmed).
// ws (floats): flag[16] | c_k[32768] | c_q[32768] | ksum01[4][32768] (pad[2] reuses)
//   | kvf01[4][16][64][2048] f32 (po[2] reuses) | ksumW[32768] | kvT bf16[16][64][2048]
// R16: traffic+TLP round. R15: kv fixed (<=49us); out now the wall (50us, WRITE 46.5MB
//     dominated by 33.5MB f32 po partials). Changes: (1) out sp=2 (128-row blocks,
//     8 waves = 4 lc x 2 mspl, fin mspl-reduce) -> po/pad traffic halved, still 2 blk/CU;
//     (2) stats 512-thr blocks (2 blk/CU TLP, R15-kv pattern); (3) out2 2-split.
//     kv/reduce/detect unchanged from R15 (proven).

#define LL 2048
#define HH 8
#define MM 2048
#define ROWSTR 512  // HH*64

#define NORMC 0.35355339059327373f   // 64^-0.25
#define LOG2E 1.4426950408889634f
#define NORMC2 (NORMC * LOG2E)
#define RATIO 0.022097086912079608f  // 2048^-0.5
#define KEPS 1e-4f
#define REPS (RATIO * KEPS)
#define EPSD 1e-6f

#define KVSPLIT 2097152
#define RSPLIT 32768

typedef __attribute__((ext_vector_type(8))) short short8;
typedef __attribute__((ext_vector_type(16))) float f32x16;

#define MFMA32(a, b, c) __builtin_amdgcn_mfma_f32_32x32x16_bf16((a), (b), (c), 0, 0, 0)

// LDS-only workgroup barrier: drains lgkmcnt but leaves global loads in flight.
__device__ __forceinline__ void wg_barrier_lds() {
    asm volatile("s_waitcnt lgkmcnt(0)" ::: "memory");
    __builtin_amdgcn_s_barrier();
    __builtin_amdgcn_sched_barrier(0);
}

__device__ __forceinline__ f32x16 zero16() {
    f32x16 v;
    #pragma unroll
    for (int i = 0; i < 16; ++i) v[i] = 0.f;
    return v;
}
__device__ __forceinline__ unsigned short f2bf(float f) {  // RNE
    union { float f; unsigned int u; } v; v.f = f;
    unsigned int r = v.u + 0x7fffu + ((v.u >> 16) & 1u);
    return (unsigned short)(r >> 16);
}
__device__ __forceinline__ unsigned int pk2(float lo, float hi) {  // trunc pack
    return __builtin_amdgcn_perm(__float_as_uint(hi), __float_as_uint(lo), 0x07060302u);
}
__device__ __forceinline__ float bf2f(unsigned short u) {
    union { unsigned int ui; float f; } v; v.ui = ((unsigned int)u) << 16; return v.f;
}

// ---- direct global row-fragment load: 8 bf16 at row*stride + off ----
template <bool BF16>
__device__ __forceinline__ short8 row_load8(const void* src, size_t rowbase, int off) {
    if (BF16) {
        return *(const short8*)((const unsigned short*)src + rowbase + off);
    } else {
        const float* p = (const float*)src + rowbase + off;
        float4 f0 = ((const float4*)p)[0], f1 = ((const float4*)p)[1];
        union { unsigned int u[4]; short8 s; } v;
        v.u[0] = pk2(f0.x, f0.y); v.u[1] = pk2(f0.z, f0.w);
        v.u[2] = pk2(f1.x, f1.y); v.u[3] = pk2(f1.z, f1.w);
        return v.s;
    }
}

// ---- 64x64 tile staging into LDS [64][72] bf16 (256-thread pattern) ----
template <bool BF16>
__device__ __forceinline__ void tile_load(const void* src, size_t base, size_t rstride,
                                          int t, uint4& A, uint4& B) {
    const int row = t >> 2, c16 = (t & 3) * 16;
    if (BF16) {
        const unsigned short* p = (const unsigned short*)src + base + (size_t)row * rstride + c16;
        A = *(const uint4*)p;
        B = *(const uint4*)(p + 8);
    } else {
        const float* p = (const float*)src + base + (size_t)row * rstride + c16;
        float4 f0 = ((const float4*)p)[0], f1 = ((const float4*)p)[1];
        float4 f2 = ((const float4*)p)[2], f3 = ((const float4*)p)[3];
        A.x = pk2(f0.x, f0.y); A.y = pk2(f0.z, f0.w);
        A.z = pk2(f1.x, f1.y); A.w = pk2(f1.z, f1.w);
        B.x = pk2(f2.x, f2.y); B.y = pk2(f2.z, f2.w);
        B.z = pk2(f3.x, f3.y); B.w = pk2(f3.z, f3.w);
    }
}
__device__ __forceinline__ void tile_store72(unsigned short* D, int t, uint4 A, uint4 B) {
    const int row = t >> 2, c16 = (t & 3) * 16;
    *(uint4*)&D[row * 72 + c16] = A;
    *(uint4*)&D[row * 72 + c16 + 8] = B;
}

// ---- V transpose staging into LDS [64e][72] (256-thread pattern) ----
template <bool BF16>
__device__ __forceinline__ void vt_load(const void* V, size_t base, int t, uint4& A, uint4& B) {
    const int s0 = (t & 31) * 2, e0 = (t >> 5) * 8;
    if (BF16) {
        const unsigned short* p = (const unsigned short*)V + base + (size_t)s0 * ROWSTR + e0;
        A = *(const uint4*)p;
        B = *(const uint4*)(p + ROWSTR);
    } else {
        const float* p = (const float*)V + base + (size_t)s0 * ROWSTR + e0;
        float4 f0 = ((const float4*)p)[0], f1 = ((const float4*)p)[1];
        const float* q = p + ROWSTR;
        float4 g0 = ((const float4*)q)[0], g1 = ((const float4*)q)[1];
        A.x = pk2(f0.x, f0.y); A.y = pk2(f0.z, f0.w);
        A.z = pk2(f1.x, f1.y); A.w = pk2(f1.z, f1.w);
        B.x = pk2(g0.x, g0.y); B.y = pk2(g0.z, g0.w);
        B.z = pk2(g1.x, g1.y); B.w = pk2(g1.z, g1.w);
    }
}
__device__ __forceinline__ void vt_store72(unsigned short* VT, int t, uint4 A, uint4 B) {
    const int s0 = (t & 31) * 2, e0 = (t >> 5) * 8;
    const unsigned ua[4] = {A.x, A.y, A.z, A.w}, ub[4] = {B.x, B.y, B.z, B.w};
    #pragma unroll
    for (int i = 0; i < 4; ++i) {
        *(unsigned*)&VT[(e0 + 2 * i) * 72 + s0] = (ua[i] & 0xFFFFu) | (ub[i] << 16);
        *(unsigned*)&VT[(e0 + 2 * i + 1) * 72 + s0] = (ua[i] >> 16) | (ub[i] & 0xFFFF0000u);
    }
}

// ---- D-layout -> B-operand exchange (half-wave) ----
__device__ __forceinline__ short8 xfrag(const unsigned int pd[8], int cp, int hi) {
    const unsigned int s0 = hi ? pd[4 * cp + 0] : pd[4 * cp + 2];
    const unsigned int s1 = hi ? pd[4 * cp + 1] : pd[4 * cp + 3];
    const unsigned int r0 = (unsigned int)__shfl_xor((int)s0, 32);
    const unsigned int r1 = (unsigned int)__shfl_xor((int)s1, 32);
    union { unsigned int u[4]; short8 s; } v;
    v.u[0] = hi ? r0 : pd[4 * cp + 0];
    v.u[1] = hi ? r1 : pd[4 * cp + 1];
    v.u[2] = hi ? pd[4 * cp + 2] : r0;
    v.u[3] = hi ? pd[4 * cp + 3] : r1;
    return v.s;
}

// ---------------- dtype detection ----------------
__global__ void LinearAttention_15985868276494_detect(const unsigned short* __restrict__ P,
                                                      float* __restrict__ flag) {
    if (threadIdx.x == 0) {
        int sane = 1;
        #pragma unroll
        for (int i = 0; i < 16; ++i) {
            const unsigned e = (P[2 * i] >> 7) & 0xFF;
            if (e < 101 || e > 141) sane = 0;
        }
        *flag = sane ? 1.0f : 0.0f;
    }
}

// ---------------- stats: c[nh][l]*log2e, 128 rows/block, 32 P-tile stream ----------------
// 512 blocks x 512 thr (8 waves), 2 blk/CU. Waves: mstrip=w&1, r3=w>>1 (32-row chunk).
// X fragments direct from global; P staged double-buffered by t<256.
// LDS: Ps[2][4608] shorts | red[256] f32  (19456 B).
template <bool BF16>
__device__ void stats_impl(const void* X, const void* P, float* cws, char* smem) {
    unsigned short* Ps = (unsigned short*)smem;        // [2][4608]
    float* red = (float*)(smem + 18432);               // [256]
    const int t = threadIdx.x;
    const int w = t >> 6, ln = t & 31, hi = (t >> 5) & 1;
    const int mstrip = w & 1, r3 = w >> 1;
    const int row_base = blockIdx.x * 128;

    short8 xb[4];
    #pragma unroll
    for (int c = 0; c < 4; ++c)
        xb[c] = row_load8<BF16>(X, (size_t)(row_base + r3 * 32 + ln) * 64, 16 * c + 8 * hi);

    const bool stP = (t < 256);
    const int tl = t & 255;
    uint4 pA, pB;
    if (stP) {
        uint4 a0, b0;
        tile_load<BF16>(P, 0, 64, tl, a0, b0);
        tile_store72(Ps, tl, a0, b0);
        tile_load<BF16>(P, (size_t)64 * 64, 64, tl, pA, pB);
    }
    wg_barrier_lds();

    float rmax = -3e38f;
    for (int i = 0; i < 32; ++i) {
        const int cur = i & 1;
        unsigned short* Pc = Ps + cur * 4608;
        f32x16 acc = zero16();
        #pragma unroll
        for (int c = 0; c < 4; ++c) {
            const short8 af = *(const short8*)&Pc[(32 * mstrip + ln) * 72 + 16 * c + 8 * hi];
            acc = MFMA32(af, xb[c], acc);
        }
        if (stP && i + 1 < 32) {
            tile_store72(Ps + (cur ^ 1) * 4608, tl, pA, pB);
            if (i + 2 < 32)
                tile_load<BF16>(P, (size_t)((i + 2) * 64) * 64, 64, tl, pA, pB);
        }
        #pragma unroll
        for (int r = 0; r < 16; ++r) rmax = fmaxf(rmax, acc[r]);
        wg_barrier_lds();
    }
    rmax = fmaxf(rmax, __shfl_xor(rmax, 32));
    if (hi == 0) red[w * 32 + ln] = rmax;
    float s2 = 0.f;
    if (mstrip == 0) {
        #pragma unroll
        for (int c = 0; c < 4; ++c) {
            union { short8 s; unsigned int u[4]; } uv; uv.s = xb[c];
            #pragma unroll
            for (int i2 = 0; i2 < 4; ++i2) {
                const float lo = bf2f((unsigned short)(uv.u[i2] & 0xFFFF));
                const float hv = bf2f((unsigned short)(uv.u[i2] >> 16));
                s2 = fmaf(lo, lo, s2); s2 = fmaf(hv, hv, s2);
            }
        }
        s2 += __shfl_xor(s2, 32);
    }
    wg_barrier_lds();
    if (mstrip == 0 && hi == 0) {
        const float rm = fmaxf(red[w * 32 + ln], red[(w + 1) * 32 + ln]);
        const int rg = row_base + r3 * 32 + ln;
        const int n = rg >> 14, l = (rg >> 3) & 2047, h = rg & 7;
        cws[(size_t)((n << 3) | h) * LL + l] =
            (NORMC * rm + (0.5f * NORMC * NORMC) * s2) * LOG2E;
    }
}

__global__ __launch_bounds__(512, 4) void LinearAttention_15985868276494_stats(
        const void* K, const void* Q, const void* P, const float* flag,
        float* c_k, float* c_q) {
    extern __shared__ char smem_st[];
    const void* X = (blockIdx.y == 0) ? K : Q;
    float* cws = (blockIdx.y == 0) ? c_k : c_q;
    if (*flag != 0.f) stats_impl<true>(X, P, cws, smem_st);
    else stats_impl<false>(X, P, cws, smem_st);
}

// ---------------- kv: partial kvf[sp][nh][e][m] f32, ksum01 (sp in 0..3) ----------------
// (unchanged from R15 — proven) 512 blocks x 512 thr, 2 blk/CU.
template <bool BF16>
__device__ void kv_impl(const void* K, const void* V, const void* P, const float* cws,
                        float* kvf01, float* ksum01, char* smem) {
    unsigned short* Ks = (unsigned short*)smem;            // [2][4608]
    unsigned short* VT = (unsigned short*)(smem + 18432);  // [2][4608]
    float* cks = (float*)(smem + 36864);                   // [2][64]

    const int t = threadIdx.x;
    const int w = t >> 6, ln = t & 31, hi = (t >> 5) & 1;
    const int mc = w;  // 32-m chunk in [0,8)
    const int bid = blockIdx.x;
    const int xcd = bid & 7, rr = bid >> 3;
    const int gq = rr >> 3, mtb = rr & 7;
    const int g = gq * 8 + xcd;
    const int nh = g >> 2, sp = g & 3;
    const int n = nh >> 3, h = nh & 7;
    const size_t xbase = (size_t)n * (LL * ROWSTR) + (size_t)h * 64;
    const int st0 = sp * 8;
    const int mbase = mtb * 256;

    const bool stK = (t < 256);
    const int tl = t & 255;

    short8 pb[4];
    #pragma unroll
    for (int c = 0; c < 4; ++c)
        pb[c] = row_load8<BF16>(P, (size_t)(mbase + mc * 32 + ln) * 64, 16 * c + 8 * hi);

    uint4 kA, kB, vA, vB; float ckr = 0.f;
    if (stK) {
        tile_load<BF16>(K, xbase + (size_t)(st0 * 64) * ROWSTR, ROWSTR, tl, kA, kB);
        tile_store72(Ks, tl, kA, kB);
        tile_load<BF16>(K, xbase + (size_t)((st0 + 1) * 64) * ROWSTR, ROWSTR, tl, kA, kB);
    } else {
        vt_load<BF16>(V, xbase + (size_t)(st0 * 64) * ROWSTR, tl, vA, vB);
        vt_store72(VT, tl, vA, vB);
        vt_load<BF16>(V, xbase + (size_t)((st0 + 1) * 64) * ROWSTR, tl, vA, vB);
    }
    if (t < 64) {
        cks[t] = cws[(size_t)nh * LL + st0 * 64 + t];
        ckr = cws[(size_t)nh * LL + (st0 + 1) * 64 + t];
    }
    wg_barrier_lds();

    f32x16 akv0 = zero16(), akv1 = zero16();
    float ks = 0.f;

    for (int i = 0; i < 8; ++i) {
        const int cur = i & 1;
        unsigned short* Kc = Ks + cur * 4608;
        unsigned short* Vc = VT + cur * 4608;
        const float* cc = cks + cur * 64;
        #pragma unroll
        for (int ss = 0; ss < 2; ++ss) {
            f32x16 D = zero16();
            #pragma unroll
            for (int c = 0; c < 4; ++c) {
                const short8 af = *(const short8*)&Kc[(32 * ss + ln) * 72 + 16 * c + 8 * hi];
                D = MFMA32(af, pb[c], D);
            }
            if (ss == 0 && i + 1 < 8) {
                if (stK) tile_store72(Ks + (cur ^ 1) * 4608, tl, kA, kB);
                else vt_store72(VT + (cur ^ 1) * 4608, tl, vA, vB);
                if (t < 64) cks[(cur ^ 1) * 64 + t] = ckr;
                if (i + 2 < 8) {
                    const int st = st0 + i + 2;
                    if (stK) tile_load<BF16>(K, xbase + (size_t)(st * 64) * ROWSTR, ROWSTR, tl, kA, kB);
                    else vt_load<BF16>(V, xbase + (size_t)(st * 64) * ROWSTR, tl, vA, vB);
                    if (t < 64) ckr = cws[(size_t)nh * LL + st * 64 + t];
                }
            }
            unsigned int pd[8];
            #pragma unroll
            for (int gIdx = 0; gIdx < 4; ++gIdx) {
                const float4 c4 = *(const float4*)&cc[32 * ss + 8 * gIdx + 4 * hi];
                const float ca[4] = {c4.x, c4.y, c4.z, c4.w};
                float f[4];
                #pragma unroll
                for (int b = 0; b < 4; ++b) {
                    const float arg = fminf(fmaf(D[4 * gIdx + b], NORMC2, -ca[b]), 0.f);
                    f[b] = fmaf(__builtin_amdgcn_exp2f(arg), RATIO, REPS);
                }
                ks += (f[0] + f[1]) + (f[2] + f[3]);
                pd[2 * gIdx] = pk2(f[0], f[1]);
                pd[2 * gIdx + 1] = pk2(f[2], f[3]);
            }
            #pragma unroll
            for (int cp = 0; cp < 2; ++cp) {
                const short8 bf = xfrag(pd, cp, hi);
                const int scol = 32 * ss + 16 * cp + 8 * hi;
                const short8 v0 = *(const short8*)&Vc[ln * 72 + scol];
                const short8 v1 = *(const short8*)&Vc[(32 + ln) * 72 + scol];
                akv0 = MFMA32(v0, bf, akv0);
                akv1 = MFMA32(v1, bf, akv1);
            }
        }
        wg_barrier_lds();
    }
    {
        ks += __shfl_xor(ks, 32);
        const int m = mbase + mc * 32 + ln;
        if (hi == 0)
            ksum01[(size_t)sp * RSPLIT + (size_t)nh * MM + m] = ks;
        float* basep = kvf01 + (size_t)sp * KVSPLIT + (size_t)nh * (size_t)(64 * MM) + m;
        #pragma unroll
        for (int r = 0; r < 16; ++r) {
            const int e = (r & 3) + 8 * (r >> 2) + 4 * hi;
            basep[(size_t)e * MM] = akv0[r];
            basep[(size_t)(e + 32) * MM] = akv1[r];
        }
    }
}

__global__ __launch_bounds__(512, 4) void LinearAttention_15985868276494_kv(
        const void* K, const void* V, const void* P, const float* flag,
        const float* cws, float* kvf01, float* ksum01) {
    extern __shared__ char smem_kv[];
    if (*flag != 0.f) kv_impl<true>(K, V, P, cws, kvf01, ksum01, smem_kv);
    else kv_impl<false>(K, V, P, cws, kvf01, ksum01, smem_kv);
}

// ---------------- reduce: kvT bf16 = sum of 4 splits; ksumW ----------------
__global__ __launch_bounds__(256) void LinearAttention_15985868276494_reduce(
        const float* __restrict__ kvf01, const float* __restrict__ ksum01,
        unsigned short* __restrict__ kvT, float* __restrict__ ksumW) {
    const int gid = blockIdx.x * 256 + threadIdx.x;
    const size_t i4 = (size_t)gid * 4;
    const float4 a = *(const float4*)&kvf01[i4];
    const float4 b = *(const float4*)&kvf01[KVSPLIT + i4];
    const float4 c = *(const float4*)&kvf01[2 * (size_t)KVSPLIT + i4];
    const float4 d = *(const float4*)&kvf01[3 * (size_t)KVSPLIT + i4];
    uint2 o;
    o.x = (unsigned)f2bf(a.x + b.x + c.x + d.x) | ((unsigned)f2bf(a.y + b.y + c.y + d.y) << 16);
    o.y = (unsigned)f2bf(a.z + b.z + c.z + d.z) | ((unsigned)f2bf(a.w + b.w + c.w + d.w) << 16);
    *(uint2*)&kvT[i4] = o;
    if (blockIdx.x < 32) {
        const float4 e = *(const float4*)&ksum01[i4];
        const float4 f = *(const float4*)&ksum01[RSPLIT + i4];
        const float4 g = *(const float4*)&ksum01[2 * RSPLIT + i4];
        const float4 h = *(const float4*)&ksum01[3 * RSPLIT + i4];
        *(float4*)&ksumW[i4] = make_float4(e.x + f.x + g.x + h.x, e.y + f.y + g.y + h.y,
                                           e.z + f.z + g.z + h.z, e.w + f.w + g.w + h.w);
    }
}

// ---------------- out (partial over m-half sp in 0..1): po f32, pad f32 ----------------
// 512 blocks x 512 thr, 2 blk/CU. Block owns 128 l-rows; streams 16 m-tiles (sp half).
// Decode: xcd=bid&7, rr=bid>>3, gq=rr>>4, lbb=rr&15, g=gq*8+xcd, nh=g>>1, sp=g&1.
// Waves: lc=w&3 (32-l chunk), mspl=w>>2 (m-strip of tile); mspl pair combined via fin.
// LDS: Ps[2][4608] | KVs[2][4608] | kss[2][64]; fin[4*64*33] aliases (epilogue only).
template <bool BF16>
__device__ void out_impl(const void* Q, const void* P, const float* cqw,
                         const unsigned short* kvT, const float* ksum,
                         float* po, float* pad, char* smem) {
    unsigned short* Ps = (unsigned short*)smem;              // [2][4608]
    unsigned short* KVs = (unsigned short*)(smem + 18432);   // [2][4608]
    unsigned short* kss = (unsigned short*)(smem + 36864);   // [2][64]
    float* fin = (float*)smem;                               // [4*64*33]

    const int t = threadIdx.x;
    const int w = t >> 6, ln = t & 31, hi = (t >> 5) & 1;
    const int lc = w & 3, mspl = w >> 2;
    const int bid = blockIdx.x;
    const int xcd = bid & 7, rr = bid >> 3;
    const int gq = rr >> 4, lbb = rr & 15;
    const int g = gq * 8 + xcd;
    const int nh = g >> 1, sp = g & 1;
    const int n = nh >> 3, h = nh & 7;
    const size_t qbase = (size_t)n * (LL * ROWSTR) + (size_t)h * 64;
    const size_t kvbase = (size_t)nh * (size_t)(64 * MM);
    const int mt0 = sp * 16;
    const int lbase = lbb * 128;

    const bool stP = (t < 256);
    const int tl = t & 255;

    // Q fragments direct from global (rows l = lbase + lc*32 + ln)
    short8 qb[4];
    #pragma unroll
    for (int c = 0; c < 4; ++c)
        qb[c] = row_load8<BF16>(Q, qbase + (size_t)(lbase + lc * 32 + ln) * ROWSTR, 16 * c + 8 * hi);
    const float cq = cqw[(size_t)nh * LL + lbase + lc * 32 + ln];

    uint4 pA, pB, kA, kB; float ksr = 0.f;
    if (stP) {
        tile_load<BF16>(P, (size_t)(mt0 * 64) * 64, 64, tl, pA, pB);
        tile_store72(Ps, tl, pA, pB);
        tile_load<BF16>(P, (size_t)((mt0 + 1) * 64) * 64, 64, tl, pA, pB);
    } else {
        tile_load<true>(kvT, kvbase + mt0 * 64, MM, tl, kA, kB);
        tile_store72(KVs, tl, kA, kB);
        tile_load<true>(kvT, kvbase + (mt0 + 1) * 64, MM, tl, kA, kB);
    }
    if (t < 64) {
        kss[t] = f2bf(ksum[(size_t)nh * MM + mt0 * 64 + t]);
        ksr = ksum[(size_t)nh * MM + (mt0 + 1) * 64 + t];
    }
    wg_barrier_lds();

    f32x16 ao0 = zero16(), ao1 = zero16(), ad = zero16();

    for (int i = 0; i < 16; ++i) {
        const int cur = i & 1;
        unsigned short* Pc = Ps + cur * 4608;
        unsigned short* Kc = KVs + cur * 4608;
        const unsigned short* ksc = kss + cur * 64;
        // gemm1: D[m][l] for this wave's m-strip (mspl)
        f32x16 D = zero16();
        #pragma unroll
        for (int c = 0; c < 4; ++c) {
            const short8 af = *(const short8*)&Pc[(32 * mspl + ln) * 72 + 16 * c + 8 * hi];
            D = MFMA32(af, qb[c], D);
        }
        // staging
        if (i + 1 < 16) {
            if (stP) tile_store72(Ps + (cur ^ 1) * 4608, tl, pA, pB);
            else tile_store72(KVs + (cur ^ 1) * 4608, tl, kA, kB);
            if (t < 64) kss[(cur ^ 1) * 64 + t] = f2bf(ksr);
            if (i + 2 < 16) {
                if (stP) tile_load<BF16>(P, (size_t)((mt0 + i + 2) * 64) * 64, 64, tl, pA, pB);
                else tile_load<true>(kvT, kvbase + (mt0 + i + 2) * 64, MM, tl, kA, kB);
                if (t < 64) ksr = ksum[(size_t)nh * MM + (mt0 + i + 2) * 64 + t];
            }
        }
        // exp2 (cq depends on l = col only)
        unsigned int pd[8];
        #pragma unroll
        for (int gIdx = 0; gIdx < 4; ++gIdx) {
            float f[4];
            #pragma unroll
            for (int b = 0; b < 4; ++b) {
                const float arg = fminf(fmaf(D[4 * gIdx + b], NORMC2, -cq), 0.f);
                f[b] = fmaf(__builtin_amdgcn_exp2f(arg), RATIO, REPS);
            }
            pd[2 * gIdx] = pk2(f[0], f[1]);
            pd[2 * gIdx + 1] = pk2(f[2], f[3]);
        }
        // gemm2: O[e][l] += KV . F ; ad[.][l] += ksum . F  (this m-strip only)
        #pragma unroll
        for (int cp = 0; cp < 2; ++cp) {
            const short8 bf = xfrag(pd, cp, hi);
            const int mcol = 32 * mspl + 16 * cp + 8 * hi;
            const short8 a0 = *(const short8*)&Kc[ln * 72 + mcol];
            const short8 a1 = *(const short8*)&Kc[(32 + ln) * 72 + mcol];
            const short8 k8 = *(const short8*)&ksc[mcol];
            ao0 = MFMA32(a0, bf, ao0);
            ao1 = MFMA32(a1, bf, ao1);
            ad = MFMA32(k8, bf, ad);
        }
        wg_barrier_lds();
    }
    // epilogue: 2 epochs of 64 l-rows; combine mspl pairs via fin, write po/pad
    #pragma unroll 1
    for (int e2 = 0; e2 < 2; ++e2) {
        if ((lc >> 1) == e2) {
            const int slot = ((lc & 1) * 2 + mspl);
            const int addr = (slot * 64 + (t & 63)) * 33;
            #pragma unroll
            for (int r = 0; r < 16; ++r) fin[addr + r] = ao0[r];
            #pragma unroll
            for (int r = 0; r < 16; ++r) fin[addr + 16 + r] = ao1[r];
            fin[addr + 32] = ad[0];
        }
        wg_barrier_lds();
        {
            // 512 threads cover 64 l-rows x 64 e (8 e per thread)
            const int l64 = t >> 3, eg = t & 7;
            const int lcl = l64 >> 5, lane_l = l64 & 31;
            const int s0 = (lcl * 2) * 64, s1 = (lcl * 2 + 1) * 64;
            const float adt = fin[(s0 + lane_l) * 33 + 32] + fin[(s1 + lane_l) * 33 + 32];
            const int l = lbase + (e2 * 2 + lcl) * 32 + lane_l;
            const size_t row = (size_t)(n * LL + l) * HH + h;
            if (eg == 0) pad[(size_t)sp * RSPLIT + row] = adt;
            float* dst = po + (size_t)sp * KVSPLIT + row * 64 + eg * 8;
            #pragma unroll
            for (int jq = 0; jq < 2; ++jq) {
                float o[4];
                #pragma unroll
                for (int b = 0; b < 4; ++b) {
                    const int e = eg * 8 + 4 * jq + b;
                    const int t16 = e >> 5, e5 = e & 31;
                    const int hi_s = (e5 >> 2) & 1;
                    const int reg = 16 * t16 + (e5 & 3) + 4 * (e5 >> 3);
                    const int lane_s = hi_s * 32 + lane_l;
                    o[b] = fin[(s0 + lane_s) * 33 + reg] + fin[(s1 + lane_s) * 33 + reg];
                }
                *(float4*)&dst[4 * jq] = make_float4(o[0], o[1], o[2], o[3]);
            }
        }
        wg_barrier_lds();
    }
}

__global__ __launch_bounds__(512, 4) void LinearAttention_15985868276494_out(
        const void* Q, const void* P, const float* flag, const float* cqw,
        const unsigned short* kvT, const float* ksum, float* po, float* pad) {
    extern __shared__ char smem_out[];
    if (*flag != 0.f) out_impl<true>(Q, P, cqw, kvT, ksum, po, pad, smem_out);
    else out_impl<false>(Q, P, cqw, kvT, ksum, po, pad, smem_out);
}

// ---------------- out2: combine 2 m-halves, normalize, emit ----------------
__global__ __launch_bounds__(256) void LinearAttention_15985868276494_out2(
        const float* __restrict__ po, const float* __restrict__ pad,
        const float* __restrict__ flag, void* __restrict__ outp) {
    const int gid = blockIdx.x * 256 + threadIdx.x;
    const int row = gid >> 2, eg = gid & 3;
    const float adt = pad[row] + pad[RSPLIT + row];
    const float z = 1.0f / (adt + EPSD);
    const size_t base = (size_t)row * 64 + eg * 16;
    float vals[16];
    #pragma unroll
    for (int q4 = 0; q4 < 4; ++q4) {
        const float4 a = *(const float4*)&po[base + 4 * q4];
        const float4 b = *(const float4*)&po[KVSPLIT + base + 4 * q4];
        vals[4 * q4 + 0] = (a.x + b.x) * z;
        vals[4 * q4 + 1] = (a.y + b.y) * z;
        vals[4 * q4 + 2] = (a.z + b.z) * z;
        vals[4 * q4 + 3] = (a.w + b.w) * z;
    }
    if (*flag != 0.f) {
        uint4 o0, o1;
        o0.x = (unsigned)f2bf(vals[0]) | ((unsigned)f2bf(vals[1]) << 16);
        o0.y = (unsigned)f2bf(vals[2]) | ((unsigned)f2bf(vals[3]) << 16);
        o0.z = (unsigned)f2bf(vals[4]) | ((unsigned)f2bf(vals[5]) << 16);
        o0.w = (unsigned)f2bf(vals[6]) | ((unsigned)f2bf(vals[7]) << 16);
        o1.x = (unsigned)f2bf(vals[8]) | ((unsigned)f2bf(vals[9]) << 16);
        o1.y = (unsigned)f2bf(vals[10]) | ((unsigned)f2bf(vals[11]) << 16);
        o1.z = (unsigned)f2bf(vals[12]) | ((unsigned)f2bf(vals[13]) << 16);
        o1.w = (unsigned)f2bf(vals[14]) | ((unsigned)f2bf(vals[15]) << 16);
        unsigned short* op = (unsigned short*)outp + base;
        *(uint4*)op = o0;
        *(uint4*)(op + 8) = o1;
    } else {
        float* op = (float*)outp + base;
        #pragma unroll
        for (int q4 = 0; q4 < 4; ++q4)
            *(float4*)&op[4 * q4] = make_float4(vals[4 * q4], vals[4 * q4 + 1],
                                                vals[4 * q4 + 2], vals[4 * q4 + 3]);
    }
}

extern "C" void kernel_launch(void* const* d_in, const int* in_sizes, int n_in,
                              void* d_out, int out_size, void* d_ws, size_t ws_size,
                              hipStream_t stream) {
    const void* Q = d_in[0];
    const void* K = d_in[1];
    const void* V = d_in[2];
    const void* P = d_in[3];

    float* W = (float*)d_ws;
    float* flag = W;                                  // [16]
    float* c_k = W + 16;                              // [32768]
    float* c_q = c_k + 32768;                         // [32768]
    float* ksum01 = c_q + 32768;                      // [4][32768]; pad[2] reuses
    float* kvf01 = ksum01 + 4 * RSPLIT;               // [4][16][64][2048] f32; po[2] reuses
    float* ksumW = kvf01 + 4 * (size_t)KVSPLIT;       // [32768]
    unsigned short* kvTW = (unsigned short*)(ksumW + RSPLIT);  // [16][64][2048] bf16

    LinearAttention_15985868276494_detect<<<1, 64, 0, stream>>>(
        (const unsigned short*)P, flag);
    LinearAttention_15985868276494_stats<<<dim3(256, 2), 512, 19456, stream>>>(
        K, Q, P, flag, c_k, c_q);
    LinearAttention_15985868276494_kv<<<dim3(512), 512, 37376, stream>>>(
        K, V, P, flag, c_k, kvf01, ksum01);
    LinearAttention_15985868276494_reduce<<<2048, 256, 0, stream>>>(
        kvf01, ksum01, kvTW, ksumW);
    LinearAttention_15985868276494_out<<<dim3(512), 512, 37120, stream>>>(
        Q, P, flag, c_q, kvTW, ksumW, kvf01, ksum01);
    LinearAttention_15985868276494_out2<<<512, 256, 0, stream>>>(
        kvf01, ksum01, flag, d_out);
}

// Round 11
// 180.585 us; speedup vs baseline: 5.1724x; 1.0269x over previous
//
#include <hip/hip_runtime.h>

// Performer linear attention, 32x32x16 MFMA, register-resident features.
// n=2, l=2048, h=8, e=64, m=2048. Dtype runtime-detected (bf16 confirmed).
// ws (floats): flag[16] | c_k[32768] | c_q[32768] | ksum01[4][32768] (pad[2] reuses)
//   | kvf01[4][16][64][2048] f32 (po[2] reuses) | ksumW[32768] | kvT bf16[16][64][2048]
// R17: stagger round. R16 left out at 46us with ~7000cy/iter vs ~800cy pipe work;
//     residual = ADDRESS-LOCKSTEP same-line L2 multicast (R10 mechanism, never removed):
//     out 16-way (lbb group), stats 512-way (never treated), kv 8-way. Fix: each block
//     iterates its tile stream at offset phase=(group position), i.e. tile[(i+ph)%T] --
//     commutative accumulation, so pure index permutation. At any instant a group's
//     blocks read T DIFFERENT tiles -> no same-line bank serialization, same residency.
//     kv ph=mtb&7 (T=8), out ph=lbb (T=16), stats ph=bid&31 (T=32). Else identical R16.

#define LL 2048
#define HH 8
#define MM 2048
#define ROWSTR 512  // HH*64

#define NORMC 0.35355339059327373f   // 64^-0.25
#define LOG2E 1.4426950408889634f
#define NORMC2 (NORMC * LOG2E)
#define RATIO 0.022097086912079608f  // 2048^-0.5
#define KEPS 1e-4f
#define REPS (RATIO * KEPS)
#define EPSD 1e-6f

#define KVSPLIT 2097152
#define RSPLIT 32768

typedef __attribute__((ext_vector_type(8))) short short8;
typedef __attribute__((ext_vector_type(16))) float f32x16;

#define MFMA32(a, b, c) __builtin_amdgcn_mfma_f32_32x32x16_bf16((a), (b), (c), 0, 0, 0)

// LDS-only workgroup barrier: drains lgkmcnt but leaves global loads in flight.
__device__ __forceinline__ void wg_barrier_lds() {
    asm volatile("s_waitcnt lgkmcnt(0)" ::: "memory");
    __builtin_amdgcn_s_barrier();
    __builtin_amdgcn_sched_barrier(0);
}

__device__ __forceinline__ f32x16 zero16() {
    f32x16 v;
    #pragma unroll
    for (int i = 0; i < 16; ++i) v[i] = 0.f;
    return v;
}
__device__ __forceinline__ unsigned short f2bf(float f) {  // RNE
    union { float f; unsigned int u; } v; v.f = f;
    unsigned int r = v.u + 0x7fffu + ((v.u >> 16) & 1u);
    return (unsigned short)(r >> 16);
}
__device__ __forceinline__ unsigned int pk2(float lo, float hi) {  // trunc pack
    return __builtin_amdgcn_perm(__float_as_uint(hi), __float_as_uint(lo), 0x07060302u);
}
__device__ __forceinline__ float bf2f(unsigned short u) {
    union { unsigned int ui; float f; } v; v.ui = ((unsigned int)u) << 16; return v.f;
}

// ---- direct global row-fragment load: 8 bf16 at row*stride + off ----
template <bool BF16>
__device__ __forceinline__ short8 row_load8(const void* src, size_t rowbase, int off) {
    if (BF16) {
        return *(const short8*)((const unsigned short*)src + rowbase + off);
    } else {
        const float* p = (const float*)src + rowbase + off;
        float4 f0 = ((const float4*)p)[0], f1 = ((const float4*)p)[1];
        union { unsigned int u[4]; short8 s; } v;
        v.u[0] = pk2(f0.x, f0.y); v.u[1] = pk2(f0.z, f0.w);
        v.u[2] = pk2(f1.x, f1.y); v.u[3] = pk2(f1.z, f1.w);
        return v.s;
    }
}

// ---- 64x64 tile staging into LDS [64][72] bf16 (256-thread pattern) ----
template <bool BF16>
__device__ __forceinline__ void tile_load(const void* src, size_t base, size_t rstride,
                                          int t, uint4& A, uint4& B) {
    const int row = t >> 2, c16 = (t & 3) * 16;
    if (BF16) {
        const unsigned short* p = (const unsigned short*)src + base + (size_t)row * rstride + c16;
        A = *(const uint4*)p;
        B = *(const uint4*)(p + 8);
    } else {
        const float* p = (const float*)src + base + (size_t)row * rstride + c16;
        float4 f0 = ((const float4*)p)[0], f1 = ((const float4*)p)[1];
        float4 f2 = ((const float4*)p)[2], f3 = ((const float4*)p)[3];
        A.x = pk2(f0.x, f0.y); A.y = pk2(f0.z, f0.w);
        A.z = pk2(f1.x, f1.y); A.w = pk2(f1.z, f1.w);
        B.x = pk2(f2.x, f2.y); B.y = pk2(f2.z, f2.w);
        B.z = pk2(f3.x, f3.y); B.w = pk2(f3.z, f3.w);
    }
}
__device__ __forceinline__ void tile_store72(unsigned short* D, int t, uint4 A, uint4 B) {
    const int row = t >> 2, c16 = (t & 3) * 16;
    *(uint4*)&D[row * 72 + c16] = A;
    *(uint4*)&D[row * 72 + c16 + 8] = B;
}

// ---- V transpose staging into LDS [64e][72] (256-thread pattern) ----
template <bool BF16>
__device__ __forceinline__ void vt_load(const void* V, size_t base, int t, uint4& A, uint4& B) {
    const int s0 = (t & 31) * 2, e0 = (t >> 5) * 8;
    if (BF16) {
        const unsigned short* p = (const unsigned short*)V + base + (size_t)s0 * ROWSTR + e0;
        A = *(const uint4*)p;
        B = *(const uint4*)(p + ROWSTR);
    } else {
        const float* p = (const float*)V + base + (size_t)s0 * ROWSTR + e0;
        float4 f0 = ((const float4*)p)[0], f1 = ((const float4*)p)[1];
        const float* q = p + ROWSTR;
        float4 g0 = ((const float4*)q)[0], g1 = ((const float4*)q)[1];
        A.x = pk2(f0.x, f0.y); A.y = pk2(f0.z, f0.w);
        A.z = pk2(f1.x, f1.y); A.w = pk2(f1.z, f1.w);
        B.x = pk2(g0.x, g0.y); B.y = pk2(g0.z, g0.w);
        B.z = pk2(g1.x, g1.y); B.w = pk2(g1.z, g1.w);
    }
}
__device__ __forceinline__ void vt_store72(unsigned short* VT, int t, uint4 A, uint4 B) {
    const int s0 = (t & 31) * 2, e0 = (t >> 5) * 8;
    const unsigned ua[4] = {A.x, A.y, A.z, A.w}, ub[4] = {B.x, B.y, B.z, B.w};
    #pragma unroll
    for (int i = 0; i < 4; ++i) {
        *(unsigned*)&VT[(e0 + 2 * i) * 72 + s0] = (ua[i] & 0xFFFFu) | (ub[i] << 16);
        *(unsigned*)&VT[(e0 + 2 * i + 1) * 72 + s0] = (ua[i] >> 16) | (ub[i] & 0xFFFF0000u);
    }
}

// ---- D-layout -> B-operand exchange (half-wave) ----
__device__ __forceinline__ short8 xfrag(const unsigned int pd[8], int cp, int hi) {
    const unsigned int s0 = hi ? pd[4 * cp + 0] : pd[4 * cp + 2];
    const unsigned int s1 = hi ? pd[4 * cp + 1] : pd[4 * cp + 3];
    const unsigned int r0 = (unsigned int)__shfl_xor((int)s0, 32);
    const unsigned int r1 = (unsigned int)__shfl_xor((int)s1, 32);
    union { unsigned int u[4]; short8 s; } v;
    v.u[0] = hi ? r0 : pd[4 * cp + 0];
    v.u[1] = hi ? r1 : pd[4 * cp + 1];
    v.u[2] = hi ? pd[4 * cp + 2] : r0;
    v.u[3] = hi ? pd[4 * cp + 3] : r1;
    return v.s;
}

// ---------------- dtype detection ----------------
__global__ void LinearAttention_15985868276494_detect(const unsigned short* __restrict__ P,
                                                      float* __restrict__ flag) {
    if (threadIdx.x == 0) {
        int sane = 1;
        #pragma unroll
        for (int i = 0; i < 16; ++i) {
            const unsigned e = (P[2 * i] >> 7) & 0xFF;
            if (e < 101 || e > 141) sane = 0;
        }
        *flag = sane ? 1.0f : 0.0f;
    }
}

// ---------------- stats: c[nh][l]*log2e, 128 rows/block, 32 P-tile stream ----------------
// 512 blocks x 512 thr (8 waves), 2 blk/CU. Staggered tile order: ph = bid&31.
// LDS: Ps[2][4608] shorts | red[256] f32  (19456 B).
template <bool BF16>
__device__ void stats_impl(const void* X, const void* P, float* cws, char* smem) {
    unsigned short* Ps = (unsigned short*)smem;        // [2][4608]
    float* red = (float*)(smem + 18432);               // [256]
    const int t = threadIdx.x;
    const int w = t >> 6, ln = t & 31, hi = (t >> 5) & 1;
    const int mstrip = w & 1, r3 = w >> 1;
    const int row_base = blockIdx.x * 128;
    const int ph = blockIdx.x & 31;

    short8 xb[4];
    #pragma unroll
    for (int c = 0; c < 4; ++c)
        xb[c] = row_load8<BF16>(X, (size_t)(row_base + r3 * 32 + ln) * 64, 16 * c + 8 * hi);

    const bool stP = (t < 256);
    const int tl = t & 255;
    uint4 pA, pB;
    if (stP) {
        uint4 a0, b0;
        tile_load<BF16>(P, (size_t)(ph * 64) * 64, 64, tl, a0, b0);
        tile_store72(Ps, tl, a0, b0);
        tile_load<BF16>(P, (size_t)(((ph + 1) & 31) * 64) * 64, 64, tl, pA, pB);
    }
    wg_barrier_lds();

    float rmax = -3e38f;
    for (int i = 0; i < 32; ++i) {
        const int cur = i & 1;
        unsigned short* Pc = Ps + cur * 4608;
        f32x16 acc = zero16();
        #pragma unroll
        for (int c = 0; c < 4; ++c) {
            const short8 af = *(const short8*)&Pc[(32 * mstrip + ln) * 72 + 16 * c + 8 * hi];
            acc = MFMA32(af, xb[c], acc);
        }
        if (stP && i + 1 < 32) {
            tile_store72(Ps + (cur ^ 1) * 4608, tl, pA, pB);
            if (i + 2 < 32)
                tile_load<BF16>(P, (size_t)(((i + 2 + ph) & 31) * 64) * 64, 64, tl, pA, pB);
        }
        #pragma unroll
        for (int r = 0; r < 16; ++r) rmax = fmaxf(rmax, acc[r]);
        wg_barrier_lds();
    }
    rmax = fmaxf(rmax, __shfl_xor(rmax, 32));
    if (hi == 0) red[w * 32 + ln] = rmax;
    float s2 = 0.f;
    if (mstrip == 0) {
        #pragma unroll
        for (int c = 0; c < 4; ++c) {
            union { short8 s; unsigned int u[4]; } uv; uv.s = xb[c];
            #pragma unroll
            for (int i2 = 0; i2 < 4; ++i2) {
                const float lo = bf2f((unsigned short)(uv.u[i2] & 0xFFFF));
                const float hv = bf2f((unsigned short)(uv.u[i2] >> 16));
                s2 = fmaf(lo, lo, s2); s2 = fmaf(hv, hv, s2);
            }
        }
        s2 += __shfl_xor(s2, 32);
    }
    wg_barrier_lds();
    if (mstrip == 0 && hi == 0) {
        const float rm = fmaxf(red[w * 32 + ln], red[(w + 1) * 32 + ln]);
        const int rg = row_base + r3 * 32 + ln;
        const int n = rg >> 14, l = (rg >> 3) & 2047, h = rg & 7;
        cws[(size_t)((n << 3) | h) * LL + l] =
            (NORMC * rm + (0.5f * NORMC * NORMC) * s2) * LOG2E;
    }
}

__global__ __launch_bounds__(512, 4) void LinearAttention_15985868276494_stats(
        const void* K, const void* Q, const void* P, const float* flag,
        float* c_k, float* c_q) {
    extern __shared__ char smem_st[];
    const void* X = (blockIdx.y == 0) ? K : Q;
    float* cws = (blockIdx.y == 0) ? c_k : c_q;
    if (*flag != 0.f) stats_impl<true>(X, P, cws, smem_st);
    else stats_impl<false>(X, P, cws, smem_st);
}

// ---------------- kv: partial kvf[sp][nh][e][m] f32, ksum01 (sp in 0..3) ----------------
// 512 blocks x 512 thr, 2 blk/CU. Staggered s-tile order: ph = mtb&7 (T=8).
template <bool BF16>
__device__ void kv_impl(const void* K, const void* V, const void* P, const float* cws,
                        float* kvf01, float* ksum01, char* smem) {
    unsigned short* Ks = (unsigned short*)smem;            // [2][4608]
    unsigned short* VT = (unsigned short*)(smem + 18432);  // [2][4608]
    float* cks = (float*)(smem + 36864);                   // [2][64]

    const int t = threadIdx.x;
    const int w = t >> 6, ln = t & 31, hi = (t >> 5) & 1;
    const int mc = w;  // 32-m chunk in [0,8)
    const int bid = blockIdx.x;
    const int xcd = bid & 7, rr = bid >> 3;
    const int gq = rr >> 3, mtb = rr & 7;
    const int g = gq * 8 + xcd;
    const int nh = g >> 2, sp = g & 3;
    const int n = nh >> 3, h = nh & 7;
    const size_t xbase = (size_t)n * (LL * ROWSTR) + (size_t)h * 64;
    const int st0 = sp * 8;
    const int mbase = mtb * 256;
    const int ph = mtb & 7;

    const bool stK = (t < 256);
    const int tl = t & 255;

    short8 pb[4];
    #pragma unroll
    for (int c = 0; c < 4; ++c)
        pb[c] = row_load8<BF16>(P, (size_t)(mbase + mc * 32 + ln) * 64, 16 * c + 8 * hi);

    uint4 kA, kB, vA, vB; float ckr = 0.f;
    {
        const int s_a = st0 + ph, s_b = st0 + ((ph + 1) & 7);
        if (stK) {
            tile_load<BF16>(K, xbase + (size_t)(s_a * 64) * ROWSTR, ROWSTR, tl, kA, kB);
            tile_store72(Ks, tl, kA, kB);
            tile_load<BF16>(K, xbase + (size_t)(s_b * 64) * ROWSTR, ROWSTR, tl, kA, kB);
        } else {
            vt_load<BF16>(V, xbase + (size_t)(s_a * 64) * ROWSTR, tl, vA, vB);
            vt_store72(VT, tl, vA, vB);
            vt_load<BF16>(V, xbase + (size_t)(s_b * 64) * ROWSTR, tl, vA, vB);
        }
        if (t < 64) {
            cks[t] = cws[(size_t)nh * LL + s_a * 64 + t];
            ckr = cws[(size_t)nh * LL + s_b * 64 + t];
        }
    }
    wg_barrier_lds();

    f32x16 akv0 = zero16(), akv1 = zero16();
    float ks = 0.f;

    for (int i = 0; i < 8; ++i) {
        const int cur = i & 1;
        unsigned short* Kc = Ks + cur * 4608;
        unsigned short* Vc = VT + cur * 4608;
        const float* cc = cks + cur * 64;
        #pragma unroll
        for (int ss = 0; ss < 2; ++ss) {
            f32x16 D = zero16();
            #pragma unroll
            for (int c = 0; c < 4; ++c) {
                const short8 af = *(const short8*)&Kc[(32 * ss + ln) * 72 + 16 * c + 8 * hi];
                D = MFMA32(af, pb[c], D);
            }
            if (ss == 0 && i + 1 < 8) {
                if (stK) tile_store72(Ks + (cur ^ 1) * 4608, tl, kA, kB);
                else vt_store72(VT + (cur ^ 1) * 4608, tl, vA, vB);
                if (t < 64) cks[(cur ^ 1) * 64 + t] = ckr;
                if (i + 2 < 8) {
                    const int st = st0 + ((i + 2 + ph) & 7);
                    if (stK) tile_load<BF16>(K, xbase + (size_t)(st * 64) * ROWSTR, ROWSTR, tl, kA, kB);
                    else vt_load<BF16>(V, xbase + (size_t)(st * 64) * ROWSTR, tl, vA, vB);
                    if (t < 64) ckr = cws[(size_t)nh * LL + st * 64 + t];
                }
            }
            unsigned int pd[8];
            #pragma unroll
            for (int gIdx = 0; gIdx < 4; ++gIdx) {
                const float4 c4 = *(const float4*)&cc[32 * ss + 8 * gIdx + 4 * hi];
                const float ca[4] = {c4.x, c4.y, c4.z, c4.w};
                float f[4];
                #pragma unroll
                for (int b = 0; b < 4; ++b) {
                    const float arg = fminf(fmaf(D[4 * gIdx + b], NORMC2, -ca[b]), 0.f);
                    f[b] = fmaf(__builtin_amdgcn_exp2f(arg), RATIO, REPS);
                }
                ks += (f[0] + f[1]) + (f[2] + f[3]);
                pd[2 * gIdx] = pk2(f[0], f[1]);
                pd[2 * gIdx + 1] = pk2(f[2], f[3]);
            }
            #pragma unroll
            for (int cp = 0; cp < 2; ++cp) {
                const short8 bf = xfrag(pd, cp, hi);
                const int scol = 32 * ss + 16 * cp + 8 * hi;
                const short8 v0 = *(const short8*)&Vc[ln * 72 + scol];
                const short8 v1 = *(const short8*)&Vc[(32 + ln) * 72 + scol];
                akv0 = MFMA32(v0, bf, akv0);
                akv1 = MFMA32(v1, bf, akv1);
            }
        }
        wg_barrier_lds();
    }
    {
        ks += __shfl_xor(ks, 32);
        const int m = mbase + mc * 32 + ln;
        if (hi == 0)
            ksum01[(size_t)sp * RSPLIT + (size_t)nh * MM + m] = ks;
        float* basep = kvf01 + (size_t)sp * KVSPLIT + (size_t)nh * (size_t)(64 * MM) + m;
        #pragma unroll
        for (int r = 0; r < 16; ++r) {
            const int e = (r & 3) + 8 * (r >> 2) + 4 * hi;
            basep[(size_t)e * MM] = akv0[r];
            basep[(size_t)(e + 32) * MM] = akv1[r];
        }
    }
}

__global__ __launch_bounds__(512, 4) void LinearAttention_15985868276494_kv(
        const void* K, const void* V, const void* P, const float* flag,
        const float* cws, float* kvf01, float* ksum01) {
    extern __shared__ char smem_kv[];
    if (*flag != 0.f) kv_impl<true>(K, V, P, cws, kvf01, ksum01, smem_kv);
    else kv_impl<false>(K, V, P, cws, kvf01, ksum01, smem_kv);
}

// ---------------- reduce: kvT bf16 = sum of 4 splits; ksumW ----------------
__global__ __launch_bounds__(256) void LinearAttention_15985868276494_reduce(
        const float* __restrict__ kvf01, const float* __restrict__ ksum01,
        unsigned short* __restrict__ kvT, float* __restrict__ ksumW) {
    const int gid = blockIdx.x * 256 + threadIdx.x;
    const size_t i4 = (size_t)gid * 4;
    const float4 a = *(const float4*)&kvf01[i4];
    const float4 b = *(const float4*)&kvf01[KVSPLIT + i4];
    const float4 c = *(const float4*)&kvf01[2 * (size_t)KVSPLIT + i4];
    const float4 d = *(const float4*)&kvf01[3 * (size_t)KVSPLIT + i4];
    uint2 o;
    o.x = (unsigned)f2bf(a.x + b.x + c.x + d.x) | ((unsigned)f2bf(a.y + b.y + c.y + d.y) << 16);
    o.y = (unsigned)f2bf(a.z + b.z + c.z + d.z) | ((unsigned)f2bf(a.w + b.w + c.w + d.w) << 16);
    *(uint2*)&kvT[i4] = o;
    if (blockIdx.x < 32) {
        const float4 e = *(const float4*)&ksum01[i4];
        const float4 f = *(const float4*)&ksum01[RSPLIT + i4];
        const float4 g = *(const float4*)&ksum01[2 * RSPLIT + i4];
        const float4 h = *(const float4*)&ksum01[3 * RSPLIT + i4];
        *(float4*)&ksumW[i4] = make_float4(e.x + f.x + g.x + h.x, e.y + f.y + g.y + h.y,
                                           e.z + f.z + g.z + h.z, e.w + f.w + g.w + h.w);
    }
}

// ---------------- out (partial over m-half sp in 0..1): po f32, pad f32 ----------------
// 512 blocks x 512 thr, 2 blk/CU. Block owns 128 l-rows; streams 16 m-tiles (sp half),
// staggered: ph = lbb (T=16). Waves: lc=w&3, mspl=w>>2; mspl pair combined via fin.
// LDS: Ps[2][4608] | KVs[2][4608] | kss[2][64]; fin[4*64*33] aliases (epilogue only).
template <bool BF16>
__device__ void out_impl(const void* Q, const void* P, const float* cqw,
                         const unsigned short* kvT, const float* ksum,
                         float* po, float* pad, char* smem) {
    unsigned short* Ps = (unsigned short*)smem;              // [2][4608]
    unsigned short* KVs = (unsigned short*)(smem + 18432);   // [2][4608]
    unsigned short* kss = (unsigned short*)(smem + 36864);   // [2][64]
    float* fin = (float*)smem;                               // [4*64*33]

    const int t = threadIdx.x;
    const int w = t >> 6, ln = t & 31, hi = (t >> 5) & 1;
    const int lc = w & 3, mspl = w >> 2;
    const int bid = blockIdx.x;
    const int xcd = bid & 7, rr = bid >> 3;
    const int gq = rr >> 4, lbb = rr & 15;
    const int g = gq * 8 + xcd;
    const int nh = g >> 1, sp = g & 1;
    const int n = nh >> 3, h = nh & 7;
    const size_t qbase = (size_t)n * (LL * ROWSTR) + (size_t)h * 64;
    const size_t kvbase = (size_t)nh * (size_t)(64 * MM);
    const int mt0 = sp * 16;
    const int lbase = lbb * 128;
    const int ph = lbb;

    const bool stP = (t < 256);
    const int tl = t & 255;

    // Q fragments direct from global (rows l = lbase + lc*32 + ln)
    short8 qb[4];
    #pragma unroll
    for (int c = 0; c < 4; ++c)
        qb[c] = row_load8<BF16>(Q, qbase + (size_t)(lbase + lc * 32 + ln) * ROWSTR, 16 * c + 8 * hi);
    const float cq = cqw[(size_t)nh * LL + lbase + lc * 32 + ln];

    uint4 pA, pB, kA, kB; float ksr = 0.f;
    {
        const int m_a = mt0 + (ph & 15), m_b = mt0 + ((ph + 1) & 15);
        if (stP) {
            tile_load<BF16>(P, (size_t)(m_a * 64) * 64, 64, tl, pA, pB);
            tile_store72(Ps, tl, pA, pB);
            tile_load<BF16>(P, (size_t)(m_b * 64) * 64, 64, tl, pA, pB);
        } else {
            tile_load<true>(kvT, kvbase + m_a * 64, MM, tl, kA, kB);
            tile_store72(KVs, tl, kA, kB);
            tile_load<true>(kvT, kvbase + m_b * 64, MM, tl, kA, kB);
        }
        if (t < 64) {
            kss[t] = f2bf(ksum[(size_t)nh * MM + m_a * 64 + t]);
            ksr = ksum[(size_t)nh * MM + m_b * 64 + t];
        }
    }
    wg_barrier_lds();

    f32x16 ao0 = zero16(), ao1 = zero16(), ad = zero16();

    for (int i = 0; i < 16; ++i) {
        const int cur = i & 1;
        unsigned short* Pc = Ps + cur * 4608;
        unsigned short* Kc = KVs + cur * 4608;
        const unsigned short* ksc = kss + cur * 64;
        // gemm1: D[m][l] for this wave's m-strip (mspl)
        f32x16 D = zero16();
        #pragma unroll
        for (int c = 0; c < 4; ++c) {
            const short8 af = *(const short8*)&Pc[(32 * mspl + ln) * 72 + 16 * c + 8 * hi];
            D = MFMA32(af, qb[c], D);
        }
        // staging
        if (i + 1 < 16) {
            if (stP) tile_store72(Ps + (cur ^ 1) * 4608, tl, pA, pB);
            else tile_store72(KVs + (cur ^ 1) * 4608, tl, kA, kB);
            if (t < 64) kss[(cur ^ 1) * 64 + t] = f2bf(ksr);
            if (i + 2 < 16) {
                const int mt = mt0 + ((i + 2 + ph) & 15);
                if (stP) tile_load<BF16>(P, (size_t)(mt * 64) * 64, 64, tl, pA, pB);
                else tile_load<true>(kvT, kvbase + mt * 64, MM, tl, kA, kB);
                if (t < 64) ksr = ksum[(size_t)nh * MM + mt * 64 + t];
            }
        }
        // exp2 (cq depends on l = col only)
        unsigned int pd[8];
        #pragma unroll
        for (int gIdx = 0; gIdx < 4; ++gIdx) {
            float f[4];
            #pragma unroll
            for (int b = 0; b < 4; ++b) {
                const float arg = fminf(fmaf(D[4 * gIdx + b], NORMC2, -cq), 0.f);
                f[b] = fmaf(__builtin_amdgcn_exp2f(arg), RATIO, REPS);
            }
            pd[2 * gIdx] = pk2(f[0], f[1]);
            pd[2 * gIdx + 1] = pk2(f[2], f[3]);
        }
        // gemm2: O[e][l] += KV . F ; ad[.][l] += ksum . F  (this m-strip only)
        #pragma unroll
        for (int cp = 0; cp < 2; ++cp) {
            const short8 bf = xfrag(pd, cp, hi);
            const int mcol = 32 * mspl + 16 * cp + 8 * hi;
            const short8 a0 = *(const short8*)&Kc[ln * 72 + mcol];
            const short8 a1 = *(const short8*)&Kc[(32 + ln) * 72 + mcol];
            const short8 k8 = *(const short8*)&ksc[mcol];
            ao0 = MFMA32(a0, bf, ao0);
            ao1 = MFMA32(a1, bf, ao1);
            ad = MFMA32(k8, bf, ad);
        }
        wg_barrier_lds();
    }
    // epilogue: 2 epochs of 64 l-rows; combine mspl pairs via fin, write po/pad
    #pragma unroll 1
    for (int e2 = 0; e2 < 2; ++e2) {
        if ((lc >> 1) == e2) {
            const int slot = ((lc & 1) * 2 + mspl);
            const int addr = (slot * 64 + (t & 63)) * 33;
            #pragma unroll
            for (int r = 0; r < 16; ++r) fin[addr + r] = ao0[r];
            #pragma unroll
            for (int r = 0; r < 16; ++r) fin[addr + 16 + r] = ao1[r];
            fin[addr + 32] = ad[0];
        }
        wg_barrier_lds();
        {
            // 512 threads cover 64 l-rows x 64 e (8 e per thread)
            const int l64 = t >> 3, eg = t & 7;
            const int lcl = l64 >> 5, lane_l = l64 & 31;
            const int s0 = (lcl * 2) * 64, s1 = (lcl * 2 + 1) * 64;
            const float adt = fin[(s0 + lane_l) * 33 + 32] + fin[(s1 + lane_l) * 33 + 32];
            const int l = lbase + (e2 * 2 + lcl) * 32 + lane_l;
            const size_t row = (size_t)(n * LL + l) * HH + h;
            if (eg == 0) pad[(size_t)sp * RSPLIT + row] = adt;
            float* dst = po + (size_t)sp * KVSPLIT + row * 64 + eg * 8;
            #pragma unroll
            for (int jq = 0; jq < 2; ++jq) {
                float o[4];
                #pragma unroll
                for (int b = 0; b < 4; ++b) {
                    const int e = eg * 8 + 4 * jq + b;
                    const int t16 = e >> 5, e5 = e & 31;
                    const int hi_s = (e5 >> 2) & 1;
                    const int reg = 16 * t16 + (e5 & 3) + 4 * (e5 >> 3);
                    const int lane_s = hi_s * 32 + lane_l;
                    o[b] = fin[(s0 + lane_s) * 33 + reg] + fin[(s1 + lane_s) * 33 + reg];
                }
                *(float4*)&dst[4 * jq] = make_float4(o[0], o[1], o[2], o[3]);
            }
        }
        wg_barrier_lds();
    }
}

__global__ __launch_bounds__(512, 4) void LinearAttention_15985868276494_out(
        const void* Q, const void* P, const float* flag, const float* cqw,
        const unsigned short* kvT, const float* ksum, float* po, float* pad) {
    extern __shared__ char smem_out[];
    if (*flag != 0.f) out_impl<true>(Q, P, cqw, kvT, ksum, po, pad, smem_out);
    else out_impl<false>(Q, P, cqw, kvT, ksum, po, pad, smem_out);
}

// ---------------- out2: combine 2 m-halves, normalize, emit ----------------
__global__ __launch_bounds__(256) void LinearAttention_15985868276494_out2(
        const float* __restrict__ po, const float* __restrict__ pad,
        const float* __restrict__ flag, void* __restrict__ outp) {
    const int gid = blockIdx.x * 256 + threadIdx.x;
    const int row = gid >> 2, eg = gid & 3;
    const float adt = pad[row] + pad[RSPLIT + row];
    const float z = 1.0f / (adt + EPSD);
    const size_t base = (size_t)row * 64 + eg * 16;
    float vals[16];
    #pragma unroll
    for (int q4 = 0; q4 < 4; ++q4) {
        const float4 a = *(const float4*)&po[base + 4 * q4];
        const float4 b = *(const float4*)&po[KVSPLIT + base + 4 * q4];
        vals[4 * q4 + 0] = (a.x + b.x) * z;
        vals[4 * q4 + 1] = (a.y + b.y) * z;
        vals[4 * q4 + 2] = (a.z + b.z) * z;
        vals[4 * q4 + 3] = (a.w + b.w) * z;
    }
    if (*flag != 0.f) {
        uint4 o0, o1;
        o0.x = (unsigned)f2bf(vals[0]) | ((unsigned)f2bf(vals[1]) << 16);
        o0.y = (unsigned)f2bf(vals[2]) | ((unsigned)f2bf(vals[3]) << 16);
        o0.z = (unsigned)f2bf(vals[4]) | ((unsigned)f2bf(vals[5]) << 16);
        o0.w = (unsigned)f2bf(vals[6]) | ((unsigned)f2bf(vals[7]) << 16);
        o1.x = (unsigned)f2bf(vals[8]) | ((unsigned)f2bf(vals[9]) << 16);
        o1.y = (unsigned)f2bf(vals[10]) | ((unsigned)f2bf(vals[11]) << 16);
        o1.z = (unsigned)f2bf(vals[12]) | ((unsigned)f2bf(vals[13]) << 16);
        o1.w = (unsigned)f2bf(vals[14]) | ((unsigned)f2bf(vals[15]) << 16);
        unsigned short* op = (unsigned short*)outp + base;
        *(uint4*)op = o0;
        *(uint4*)(op + 8) = o1;
    } else {
        float* op = (float*)outp + base;
        #pragma unroll
        for (int q4 = 0; q4 < 4; ++q4)
            *(float4*)&op[4 * q4] = make_float4(vals[4 * q4], vals[4 * q4 + 1],
                                                vals[4 * q4 + 2], vals[4 * q4 + 3]);
    }
}

extern "C" void kernel_launch(void* const* d_in, const int* in_sizes, int n_in,
                              void* d_out, int out_size, void* d_ws, size_t ws_size,
                              hipStream_t stream) {
    const void* Q = d_in[0];
    const void* K = d_in[1];
    const void* V = d_in[2];
    const void* P = d_in[3];

    float* W = (float*)d_ws;
    float* flag = W;                                  // [16]
    float* c_k = W + 16;                              // [32768]
    float* c_q = c_k + 32768;                         // [32768]
    float* ksum01 = c_q + 32768;                      // [4][32768]; pad[2] reuses
    float* kvf01 = ksum01 + 4 * RSPLIT;               // [4][16][64][2048] f32; po[2] reuses
    float* ksumW = kvf01 + 4 * (size_t)KVSPLIT;       // [32768]
    unsigned short* kvTW = (unsigned short*)(ksumW + RSPLIT);  // [16][64][2048] bf16

    LinearAttention_15985868276494_detect<<<1, 64, 0, stream>>>(
        (const unsigned short*)P, flag);
    LinearAttention_15985868276494_stats<<<dim3(256, 2), 512, 19456, stream>>>(
        K, Q, P, flag, c_k, c_q);
    LinearAttention_15985868276494_kv<<<dim3(512), 512, 37376, stream>>>(
        K, V, P, flag, c_k, kvf01, ksum01);
    LinearAttention_15985868276494_reduce<<<2048, 256, 0, stream>>>(
        kvf01, ksum01, kvTW, ksumW);
    LinearAttention_15985868276494_out<<<dim3(512), 512, 37120, stream>>>(
        Q, P, flag, c_q, kvTW, ksumW, kvf01, ksum01);
    LinearAttention_15985868276494_out2<<<512, 256, 0, stream>>>(
        kvf01, ksum01, flag, d_out);
}